// Round 5
// baseline (527.087 us; speedup 1.0000x reference)
//
#include <hip/hip_runtime.h>

constexpr int B   = 2;
constexpr int T   = 2048;
constexpr int C   = 2048;
constexpr int H   = 32;
constexpr int HKV = 8;
constexpr int D   = 64;
constexpr float SCALE = 0.125f; // 1/sqrt(64)

typedef __attribute__((ext_vector_type(8))) short bf16x8;
typedef __attribute__((ext_vector_type(4))) float f32x4;

__device__ __forceinline__ unsigned short f2bf(float f) {
    unsigned u = __builtin_bit_cast(unsigned, f);
    u += 0x7fff + ((u >> 16) & 1);          // round-to-nearest-even
    return (unsigned short)(u >> 16);
}
__device__ __forceinline__ float bf2f(unsigned short u) {
    unsigned v = (unsigned)u << 16;
    return __builtin_bit_cast(float, v);
}
// pack two f32 -> two bf16 in one instruction (no builtin on gfx950)
__device__ __forceinline__ unsigned cvt_pk_bf16(float lo, float hi) {
    unsigned r;
    asm("v_cvt_pk_bf16_f32 %0, %1, %2" : "=v"(r) : "v"(lo), "v"(hi));
    return r;
}

typedef __attribute__((address_space(1))) const unsigned char ga_t;
typedef __attribute__((address_space(3))) unsigned char lds_t;
__device__ __forceinline__ void gl2lds16(const void* g, void* l) {
    // 16B per lane, dest = wave-uniform base + lane*16
    __builtin_amdgcn_global_load_lds((ga_t*)g, (lds_t*)l, 16, 0, 0);
}

// ---------------------------------------------------------------------------
// Fused fp32 -> bf16 cast of x + all 4 weights (outputs contiguous in ws).
// ---------------------------------------------------------------------------
__global__ __launch_bounds__(256) void cast_all_bf16(const float* __restrict__ x,
                                                     const float* __restrict__ wq,
                                                     const float* __restrict__ wk,
                                                     const float* __restrict__ wv,
                                                     const float* __restrict__ wc,
                                                     unsigned short* __restrict__ out) {
    const size_t b0 = (size_t)B * T * C;            // x end
    const size_t b1 = b0 + (size_t)H * D * C;       // Wq end
    const size_t b2 = b1 + (size_t)HKV * D * C;     // Wk end
    const size_t b3 = b2 + (size_t)HKV * D * C;     // Wv end
    size_t i = ((size_t)blockIdx.x * 256 + threadIdx.x) * 8;
    const float* src;
    size_t off;
    if (i < b0)      { src = x;  off = i; }
    else if (i < b1) { src = wq; off = i - b0; }
    else if (i < b2) { src = wk; off = i - b1; }
    else if (i < b3) { src = wv; off = i - b2; }
    else             { src = wc; off = i - b3; }
    float4 a = *(const float4*)(src + off);
    float4 b = *(const float4*)(src + off + 4);
    uint4 r;
    r.x = (unsigned)f2bf(a.x) | ((unsigned)f2bf(a.y) << 16);
    r.y = (unsigned)f2bf(a.z) | ((unsigned)f2bf(a.w) << 16);
    r.z = (unsigned)f2bf(b.x) | ((unsigned)f2bf(b.y) << 16);
    r.w = (unsigned)f2bf(b.z) | ((unsigned)f2bf(b.w) << 16);
    *(uint4*)(out + i) = r;
}

// ---------------------------------------------------------------------------
// bf16 MFMA NT GEMM (round-3 proven, unchanged)
// ---------------------------------------------------------------------------
template <typename OutT>
__device__ __forceinline__ void gemm_mfma_body(const unsigned short* __restrict__ Xh,
                                               const unsigned short* __restrict__ Wh,
                                               OutT* __restrict__ Y,
                                               int Nloc, int K, int bm, int bn) {
    __shared__ __align__(16) unsigned short As[128 * 32];
    __shared__ __align__(16) unsigned short Bs[128 * 32];
    char* AsB = (char*)As;
    char* BsB = (char*)Bs;

    const int tid  = threadIdx.x;
    const int wave = tid >> 6, lane = tid & 63;
    const int wm = (wave >> 1) * 64, wn = (wave & 1) * 64;
    const int m = lane & 15, quad = lane >> 4;

    const int r0 = tid >> 2;
    const int cs = tid & 3;
    const int cg = cs ^ (r0 & 3);
    const int wbase = (tid & 192) * 16;

    const unsigned short* gA = Xh + (size_t)(bm + r0) * K + cg * 8;
    const unsigned short* gB = Wh + (size_t)(bn + r0) * K + cg * 8;
    const size_t rowStep64 = (size_t)64 * K;

    int aoff[4], boff[4];
#pragma unroll
    for (int mt = 0; mt < 4; ++mt) {
        int ra = wm + mt * 16 + m;
        aoff[mt] = ra * 64 + ((quad ^ (ra & 3)) * 16);
        int rb = wn + mt * 16 + m;
        boff[mt] = rb * 64 + ((quad ^ (rb & 3)) * 16);
    }

    f32x4 acc[4][4];
#pragma unroll
    for (int i = 0; i < 4; ++i)
#pragma unroll
        for (int j = 0; j < 4; ++j) acc[i][j] = (f32x4){0.f, 0.f, 0.f, 0.f};

    for (int k0 = 0; k0 < K; k0 += 32) {
        gl2lds16(gA,             AsB + wbase);
        gl2lds16(gA + rowStep64, AsB + 4096 + wbase);
        gl2lds16(gB,             BsB + wbase);
        gl2lds16(gB + rowStep64, BsB + 4096 + wbase);
        gA += 32;
        gB += 32;
        __syncthreads();

        bf16x8 af[4], bfr[4];
#pragma unroll
        for (int mt = 0; mt < 4; ++mt) af[mt]  = *(const bf16x8*)(AsB + aoff[mt]);
#pragma unroll
        for (int nt = 0; nt < 4; ++nt) bfr[nt] = *(const bf16x8*)(BsB + boff[nt]);
#pragma unroll
        for (int mt = 0; mt < 4; ++mt)
#pragma unroll
            for (int nt = 0; nt < 4; ++nt)
                acc[mt][nt] = __builtin_amdgcn_mfma_f32_16x16x32_bf16(af[mt], bfr[nt],
                                                                      acc[mt][nt], 0, 0, 0);
        __syncthreads();
    }

#pragma unroll
    for (int mt = 0; mt < 4; ++mt)
#pragma unroll
        for (int r = 0; r < 4; ++r) {
            size_t row = (size_t)(bm + wm + mt * 16 + quad * 4 + r);
#pragma unroll
            for (int nt = 0; nt < 4; ++nt) {
                int col = bn + wn + nt * 16 + m;
                float v = acc[mt][nt][r];
                if constexpr (sizeof(OutT) == 2)
                    Y[row * Nloc + col] = f2bf(v);
                else
                    Y[row * Nloc + col] = v;
            }
        }
}

__global__ __launch_bounds__(256) void qkv_gemm_bf16(const unsigned short* __restrict__ Xh,
                                                     const unsigned short* __restrict__ Wqh,
                                                     const unsigned short* __restrict__ Wkh,
                                                     const unsigned short* __restrict__ Wvh,
                                                     unsigned short* __restrict__ qh,
                                                     unsigned short* __restrict__ kh,
                                                     unsigned short* __restrict__ vh) {
    int bn0 = blockIdx.x * 128;
    const unsigned short* Wsel;
    unsigned short* Ysel;
    int bnl, Nloc;
    if (bn0 < H * D)                { Wsel = Wqh; Ysel = qh; bnl = bn0;                  Nloc = H * D;   }
    else if (bn0 < H*D + HKV*D)     { Wsel = Wkh; Ysel = kh; bnl = bn0 - H * D;          Nloc = HKV * D; }
    else                            { Wsel = Wvh; Ysel = vh; bnl = bn0 - H*D - HKV*D;    Nloc = HKV * D; }
    gemm_mfma_body<unsigned short>(Xh, Wsel, Ysel, Nloc, C, blockIdx.y * 128, bnl);
}

__global__ __launch_bounds__(256) void out_gemm_bf16(const unsigned short* __restrict__ Xh,
                                                     const unsigned short* __restrict__ Wh,
                                                     float* __restrict__ Y) {
    gemm_mfma_body<float>(Xh, Wh, Y, C, C, blockIdx.y * 128, blockIdx.x * 128);
}

// ---------------------------------------------------------------------------
// Fused RoPE in-place on bf16 q and k (q gets softmax scale * log2e folded in)
// ---------------------------------------------------------------------------
__global__ void rope_fused(unsigned short* __restrict__ qh, unsigned short* __restrict__ kh,
                           const int* __restrict__ pos_ids, float qscale) {
    int idx = blockIdx.x * blockDim.x + threadIdx.x;
    const int qtotal = B * T * H * 32;
    unsigned short* buf;
    int nheads, rel;
    float sc;
    if (idx < qtotal) { buf = qh; nheads = H;   sc = qscale; rel = idx; }
    else              { buf = kh; nheads = HKV; sc = 1.0f;   rel = idx - qtotal; }
    int d = rel & 31;
    int rest = rel >> 5;                 // = (b*T + t)*nheads + h
    int t = (rest / nheads) % T;
    float pos = (float)pos_ids[t];
    int i1 = d >> 1;
    const float NEG_LF = -(2.0f / 64.0f) * 13.287712379549449f; // -2/D * log2(10000)
    float a1 = pos * exp2f(NEG_LF * (float)i1);
    float a2 = pos * exp2f(NEG_LF * (float)(i1 + 16));
    float c1 = cosf(a1), s1 = sinf(a1);
    float c2 = cosf(a2), s2 = sinf(a2);
    size_t base = (size_t)rest * D + d;
    float x1 = bf2f(buf[base]), x2 = bf2f(buf[base + 32]);
    buf[base]      = f2bf((x1 * c1 - x2 * s1) * sc);
    buf[base + 32] = f2bf((x2 * c2 + x1 * s2) * sc);
}

// ---------------------------------------------------------------------------
// V transpose bf16 [b][t][hkv][d] -> [b][hkv][d][t]
// ---------------------------------------------------------------------------
__global__ __launch_bounds__(256) void v_transpose(const unsigned short* __restrict__ vh,
                                                   unsigned short* __restrict__ vtg) {
    __shared__ unsigned short Vs[64][72];
    const int t0 = blockIdx.x * 64;
    const int hkv = blockIdx.y;
    const int b = blockIdx.z;
    const int tid = threadIdx.x;

    for (int e = tid; e < 512; e += 256) {
        int t = e >> 3, d8 = (e & 7) * 8;
        uint4 val = *(const uint4*)(vh + ((size_t)((b * T + t0 + t) * HKV) + hkv) * D + d8);
        unsigned short tmp[8];
        *(uint4*)tmp = val;
#pragma unroll
        for (int i = 0; i < 8; ++i) Vs[d8 + i][t] = tmp[i];
    }
    __syncthreads();
    for (int e = tid; e < 512; e += 256) {
        int d = e >> 3, c = e & 7;
        *(uint4*)(vtg + ((size_t)((b * HKV + hkv) * D) + d) * T + t0 + c * 8) =
            *(const uint4*)&Vs[d][c * 8];
    }
}

// ---------------------------------------------------------------------------
// bf16 MFMA flash attention v8: v6 core (64-q blocks, gl2lds staging, cvt_pk,
// defer-rescale, setprio) with the Ps LDS strip ELIMINATED:
//   P redistribution (C-frag key=16nt+4q+r  ->  A-frag key=8q+j, same query m)
//   is a pure lane permutation at fixed m: pa word i comes from lane
//   m + 32*(q&1) + 16*(i>>1), slot w[q>>1][i&1]  (16 shfl + 8 selects).
//   LDS 25.6 -> 16.4 KB  =>  8 blocks/CU (was 6, LDS-limited).
//   __launch_bounds__(256,8) pins VGPR <= 64 for the 32-wave residency.
// ---------------------------------------------------------------------------
__global__ __launch_bounds__(256, 8) void flash_attn_mfma(const unsigned short* __restrict__ Qh,
                                                          const unsigned short* __restrict__ Kh,
                                                          const unsigned short* __restrict__ Vtg,
                                                          unsigned short* __restrict__ Yh) {
    __shared__ __align__(16) unsigned short Ks[64 * 64];   // [key][d], XOR-swizzled chunks
    __shared__ __align__(16) unsigned short Vt[64 * 64];   // [d][key], XOR-swizzled chunks

    const int q0 = ((int)gridDim.x - 1 - (int)blockIdx.x) * 64;   // heavy-first
    const int h  = blockIdx.y;
    const int b  = blockIdx.z;
    const int hkv = h >> 2;
    const int tid = threadIdx.x;
    const int wave = tid >> 6;
    const int lane = tid & 63;
    const int m = lane & 15;
    const int quad = lane >> 4;

    // Q B-frags: this wave's 16 queries q0 + wave*16 + m (resident whole kernel)
    const unsigned short* qrow = Qh + ((size_t)((b * T + q0 + wave * 16 + m) * H) + h) * D;
    const bf16x8 qa0 = *(const bf16x8*)(qrow + quad * 8);
    const bf16x8 qa1 = *(const bf16x8*)(qrow + 32 + quad * 8);

    f32x4 o[4];
#pragma unroll
    for (int dt = 0; dt < 4; ++dt) o[dt] = (f32x4){0.f, 0.f, 0.f, 0.f};
    float ms = -1e30f, ls = 0.f;

    // staging: thread t -> LDS slot t*16B (row r0=t>>3, chunk cs=t&7),
    // source chunk cg = cs ^ (r0&7)  (XOR applied on the global address)
    const int r0 = tid >> 3, cs = tid & 7, cg = cs ^ (r0 & 7);
    const int wbase = (tid & 192) * 16;
    const unsigned short* gK = Kh + ((size_t)(b * T) * HKV + hkv) * D
                                  + (size_t)r0 * (HKV * D) + cg * 8;
    const unsigned short* gV = Vtg + ((size_t)(b * HKV + hkv) * D) * (size_t)T
                                   + (size_t)r0 * T + cg * 8;
    char* KsB = (char*)Ks;
    char* VtB = (char*)Vt;

    const int qmin = q0 + wave * 16;
    // P-redistribution source lanes (fixed per thread)
    const int srcLo = m + ((lane & 16) << 1);   // m + 32*(q&1)
    const int srcHi = srcLo + 16;
    const bool hiQ = quad >= 2;                 // q>>1 selects slot family

    for (int k0 = 0; k0 <= q0; k0 += 64) {
        gl2lds16(gK,                          KsB + wbase);
        gl2lds16(gK + (size_t)32 * (HKV * D), KsB + 4096 + wbase);
        gl2lds16(gV,                          VtB + wbase);
        gl2lds16(gV + (size_t)32 * T,         VtB + 4096 + wbase);
        gK += (size_t)64 * (HKV * D);
        gV += 64;
        __syncthreads();

        // ---- S^T = K · Q^T  (4 key-tiles of 16) ----
        f32x4 s[4];
        __builtin_amdgcn_s_setprio(1);
#pragma unroll
        for (int nt = 0; nt < 4; ++nt) {
            const int kmin = k0 + nt * 16;
            if (kmin > qmin + 15) {            // fully masked tile
                s[nt] = (f32x4){-1e30f, -1e30f, -1e30f, -1e30f};
                continue;
            }
            int row = nt * 16 + m;
            const bf16x8 ka0 = *(const bf16x8*)(KsB + row * 128 + ((quad ^ (m & 7)) * 16));
            const bf16x8 ka1 = *(const bf16x8*)(KsB + row * 128 + (((quad + 4) ^ (m & 7)) * 16));
            f32x4 acc = (f32x4){0.f, 0.f, 0.f, 0.f};
            acc = __builtin_amdgcn_mfma_f32_16x16x32_bf16(ka0, qa0, acc, 0, 0, 0);
            acc = __builtin_amdgcn_mfma_f32_16x16x32_bf16(ka1, qa1, acc, 0, 0, 0);
            if (kmin + 15 > qmin) {            // diagonal: elementwise mask
                int c0 = qmin - kmin + m - 4 * quad;   // mask if r > c0
#pragma unroll
                for (int r = 0; r < 4; ++r)
                    if (r > c0) acc[r] = -1e30f;
            }
            s[nt] = acc;
        }
        __builtin_amdgcn_s_setprio(0);

        // ---- base-2 online softmax (lane owns query m; reduce across quads) ----
        float mx = s[0][0];
#pragma unroll
        for (int nt = 0; nt < 4; ++nt)
#pragma unroll
            for (int r = 0; r < 4; ++r) mx = fmaxf(mx, s[nt][r]);
        mx = fmaxf(mx, __shfl_xor(mx, 16));
        mx = fmaxf(mx, __shfl_xor(mx, 32));

        // defer-rescale: only pay alpha broadcast + O rescale when the running
        // max grew by more than THR (P values stay bounded by 2^THR = 256)
        float al = 1.0f;
        if (__any(mx > ms + 8.0f)) {
            float mnew = fmaxf(ms, mx);
            al = exp2f(ms - mnew);
            ms = mnew;
            float av[4];
#pragma unroll
            for (int r = 0; r < 4; ++r)
                av[r] = __shfl(al, quad * 20 + r);   // lane with m' = quad*4+r
#pragma unroll
            for (int dt = 0; dt < 4; ++dt)
#pragma unroll
                for (int r = 0; r < 4; ++r) o[dt][r] *= av[r];
        }

        // ---- P = exp2(S - ms), packed to bf16 words (key-pairs per quad) ----
        float psum = 0.f;
        unsigned w00, w01, w10, w11, w20, w21, w30, w31;
        {
            float p0 = exp2f(s[0][0] - ms), p1 = exp2f(s[0][1] - ms);
            float p2 = exp2f(s[0][2] - ms), p3 = exp2f(s[0][3] - ms);
            psum += (p0 + p1) + (p2 + p3);
            w00 = cvt_pk_bf16(p0, p1); w01 = cvt_pk_bf16(p2, p3);
        }
        {
            float p0 = exp2f(s[1][0] - ms), p1 = exp2f(s[1][1] - ms);
            float p2 = exp2f(s[1][2] - ms), p3 = exp2f(s[1][3] - ms);
            psum += (p0 + p1) + (p2 + p3);
            w10 = cvt_pk_bf16(p0, p1); w11 = cvt_pk_bf16(p2, p3);
        }
        {
            float p0 = exp2f(s[2][0] - ms), p1 = exp2f(s[2][1] - ms);
            float p2 = exp2f(s[2][2] - ms), p3 = exp2f(s[2][3] - ms);
            psum += (p0 + p1) + (p2 + p3);
            w20 = cvt_pk_bf16(p0, p1); w21 = cvt_pk_bf16(p2, p3);
        }
        {
            float p0 = exp2f(s[3][0] - ms), p1 = exp2f(s[3][1] - ms);
            float p2 = exp2f(s[3][2] - ms), p3 = exp2f(s[3][3] - ms);
            psum += (p0 + p1) + (p2 + p3);
            w30 = cvt_pk_bf16(p0, p1); w31 = cvt_pk_bf16(p2, p3);
        }
        psum += __shfl_xor(psum, 16);
        psum += __shfl_xor(psum, 32);
        ls = ls * al + psum;

        // ---- in-register P redistribution: C-frag -> A-frag (no LDS) ----
        // pa0 word i = w[q>>1][i&1] from lane srcLo/srcHi (i>>1)
        unsigned a0 = __shfl(w00, srcLo), a1 = __shfl(w01, srcLo);
        unsigned a2 = __shfl(w00, srcHi), a3 = __shfl(w01, srcHi);
        unsigned b0 = __shfl(w10, srcLo), b1 = __shfl(w11, srcLo);
        unsigned b2 = __shfl(w10, srcHi), b3 = __shfl(w11, srcHi);
        uint4 u0;
        u0.x = hiQ ? b0 : a0; u0.y = hiQ ? b1 : a1;
        u0.z = hiQ ? b2 : a2; u0.w = hiQ ? b3 : a3;
        // pa1 word i = w[2 + (q>>1)][i&1]
        unsigned c0 = __shfl(w20, srcLo), c1 = __shfl(w21, srcLo);
        unsigned c2 = __shfl(w20, srcHi), c3 = __shfl(w21, srcHi);
        unsigned d0 = __shfl(w30, srcLo), d1 = __shfl(w31, srcLo);
        unsigned d2 = __shfl(w30, srcHi), d3 = __shfl(w31, srcHi);
        uint4 u1;
        u1.x = hiQ ? d0 : c0; u1.y = hiQ ? d1 : c1;
        u1.z = hiQ ? d2 : c2; u1.w = hiQ ? d3 : c3;
        const bf16x8 pa0 = __builtin_bit_cast(bf16x8, u0);
        const bf16x8 pa1 = __builtin_bit_cast(bf16x8, u1);

        // ---- O += P · V ----
        __builtin_amdgcn_s_setprio(1);
#pragma unroll
        for (int dt = 0; dt < 4; ++dt) {
            int vrow = dt * 16 + m;
            const bf16x8 vb0 = *(const bf16x8*)(VtB + vrow * 128 + ((quad ^ (m & 7)) * 16));
            const bf16x8 vb1 = *(const bf16x8*)(VtB + vrow * 128 + (((quad + 4) ^ (m & 7)) * 16));
            o[dt] = __builtin_amdgcn_mfma_f32_16x16x32_bf16(pa0, vb0, o[dt], 0, 0, 0);
            o[dt] = __builtin_amdgcn_mfma_f32_16x16x32_bf16(pa1, vb1, o[dt], 0, 0, 0);
        }
        __builtin_amdgcn_s_setprio(0);
        __syncthreads();   // protect Ks/Vt before restage
    }

    // ---- epilogue: O / l -> bf16 y[b][t][h][d] ----
#pragma unroll
    for (int r = 0; r < 4; ++r) {
        float lv = __shfl(ls, quad * 20 + r);
        float inv = 1.0f / lv;
        int trow = q0 + wave * 16 + quad * 4 + r;
        unsigned short* yp = Yh + ((size_t)(b * T + trow) * H + h) * D;
#pragma unroll
        for (int dt = 0; dt < 4; ++dt)
            yp[dt * 16 + m] = f2bf(o[dt][r] * inv);
    }
}

// ---------------------------------------------------------------------------
extern "C" void kernel_launch(void* const* d_in, const int* in_sizes, int n_in,
                              void* d_out, int out_size, void* d_ws, size_t ws_size,
                              hipStream_t stream) {
    const float* x  = (const float*)d_in[0];
    const float* Wq = (const float*)d_in[1];
    const float* Wk = (const float*)d_in[2];
    const float* Wv = (const float*)d_in[3];
    const float* Wc = (const float*)d_in[4];
    const int*  pos = (const int*)d_in[5];
    float* out = (float*)d_out;

    unsigned short* xh  = (unsigned short*)d_ws;           // contiguous with the 4 weight
    unsigned short* wqh = xh  + (size_t)B * T * C;         // buffers — fused cast relies on it
    unsigned short* wkh = wqh + (size_t)H * D * C;
    unsigned short* wvh = wkh + (size_t)HKV * D * C;
    unsigned short* wch = wvh + (size_t)HKV * D * C;
    unsigned short* qh  = wch + (size_t)C * C;
    unsigned short* kh  = qh  + (size_t)B * T * H * D;
    unsigned short* vh  = kh  + (size_t)B * T * HKV * D;
    unsigned short* vtg = vh  + (size_t)B * T * HKV * D;
    unsigned short* yh  = xh;                              // alias (xh dead after QKV)

    // 1) fused cast fp32 -> bf16 of x + Wq + Wk + Wv + Wc (one launch)
    const size_t cast_total = (size_t)B * T * C + (size_t)(H + 2 * HKV) * D * C + (size_t)C * C;
    cast_all_bf16<<<(unsigned)(cast_total / (256 * 8)), 256, 0, stream>>>(x, Wq, Wk, Wv, Wc, xh);

    // 2) fused QKV projection (bf16 MFMA)
    dim3 g1((H * D + 2 * HKV * D) / 128, (B * T) / 128);
    qkv_gemm_bf16<<<g1, 256, 0, stream>>>(xh, wqh, wkh, wvh, qh, kh, vh);

    // 3) fused RoPE on q (scale folded) + k; V transpose
    const float QSCALE = SCALE * 1.4426950408889634f;  // SCALE * log2(e)
    rope_fused<<<(B * T * (H + HKV) * 32) / 256, 256, 0, stream>>>(qh, kh, pos, QSCALE);
    v_transpose<<<dim3(T / 64, HKV, B), 256, 0, stream>>>(vh, vtg);

    // 4) causal GQA flash attention (64-q blocks, 8 blocks/CU)
    dim3 g2(T / 64, H, B);
    flash_attn_mfma<<<g2, 256, 0, stream>>>(qh, kh, vtg, yh);

    // 5) output projection
    dim3 g3(C / 128, (B * T) / 128);
    out_gemm_bf16<<<g3, 256, 0, stream>>>(yh, wch, out);
}

// Round 6
// 376.648 us; speedup vs baseline: 1.3994x; 1.3994x over previous
//
#include <hip/hip_runtime.h>

constexpr int B   = 2;
constexpr int T   = 2048;
constexpr int C   = 2048;
constexpr int H   = 32;
constexpr int HKV = 8;
constexpr int D   = 64;
constexpr float SCALE = 0.125f; // 1/sqrt(64)

typedef __attribute__((ext_vector_type(8))) short bf16x8;
typedef __attribute__((ext_vector_type(4))) float f32x4;

__device__ __forceinline__ unsigned short f2bf(float f) {
    unsigned u = __builtin_bit_cast(unsigned, f);
    u += 0x7fff + ((u >> 16) & 1);          // round-to-nearest-even
    return (unsigned short)(u >> 16);
}
__device__ __forceinline__ float bf2f(unsigned short u) {
    unsigned v = (unsigned)u << 16;
    return __builtin_bit_cast(float, v);
}
// pack two f32 -> two bf16 in one instruction (no builtin on gfx950)
__device__ __forceinline__ unsigned cvt_pk_bf16(float lo, float hi) {
    unsigned r;
    asm("v_cvt_pk_bf16_f32 %0, %1, %2" : "=v"(r) : "v"(lo), "v"(hi));
    return r;
}

typedef __attribute__((address_space(1))) const unsigned char ga_t;
typedef __attribute__((address_space(3))) unsigned char lds_t;
__device__ __forceinline__ void gl2lds16(const void* g, void* l) {
    // 16B per lane, dest = wave-uniform base + lane*16
    __builtin_amdgcn_global_load_lds((ga_t*)g, (lds_t*)l, 16, 0, 0);
}

// ---------------------------------------------------------------------------
// Fused fp32 -> bf16 cast of x + all 4 weights (outputs contiguous in ws).
// ---------------------------------------------------------------------------
__global__ __launch_bounds__(256) void cast_all_bf16(const float* __restrict__ x,
                                                     const float* __restrict__ wq,
                                                     const float* __restrict__ wk,
                                                     const float* __restrict__ wv,
                                                     const float* __restrict__ wc,
                                                     unsigned short* __restrict__ out) {
    const size_t b0 = (size_t)B * T * C;            // x end
    const size_t b1 = b0 + (size_t)H * D * C;       // Wq end
    const size_t b2 = b1 + (size_t)HKV * D * C;     // Wk end
    const size_t b3 = b2 + (size_t)HKV * D * C;     // Wv end
    size_t i = ((size_t)blockIdx.x * 256 + threadIdx.x) * 8;
    const float* src;
    size_t off;
    if (i < b0)      { src = x;  off = i; }
    else if (i < b1) { src = wq; off = i - b0; }
    else if (i < b2) { src = wk; off = i - b1; }
    else if (i < b3) { src = wv; off = i - b2; }
    else             { src = wc; off = i - b3; }
    float4 a = *(const float4*)(src + off);
    float4 b = *(const float4*)(src + off + 4);
    uint4 r;
    r.x = (unsigned)f2bf(a.x) | ((unsigned)f2bf(a.y) << 16);
    r.y = (unsigned)f2bf(a.z) | ((unsigned)f2bf(a.w) << 16);
    r.z = (unsigned)f2bf(b.x) | ((unsigned)f2bf(b.y) << 16);
    r.w = (unsigned)f2bf(b.z) | ((unsigned)f2bf(b.w) << 16);
    *(uint4*)(out + i) = r;
}

// ---------------------------------------------------------------------------
// bf16 MFMA NT GEMM (round-3 proven, unchanged)
// ---------------------------------------------------------------------------
template <typename OutT>
__device__ __forceinline__ void gemm_mfma_body(const unsigned short* __restrict__ Xh,
                                               const unsigned short* __restrict__ Wh,
                                               OutT* __restrict__ Y,
                                               int Nloc, int K, int bm, int bn) {
    __shared__ __align__(16) unsigned short As[128 * 32];
    __shared__ __align__(16) unsigned short Bs[128 * 32];
    char* AsB = (char*)As;
    char* BsB = (char*)Bs;

    const int tid  = threadIdx.x;
    const int wave = tid >> 6, lane = tid & 63;
    const int wm = (wave >> 1) * 64, wn = (wave & 1) * 64;
    const int m = lane & 15, quad = lane >> 4;

    const int r0 = tid >> 2;
    const int cs = tid & 3;
    const int cg = cs ^ (r0 & 3);
    const int wbase = (tid & 192) * 16;

    const unsigned short* gA = Xh + (size_t)(bm + r0) * K + cg * 8;
    const unsigned short* gB = Wh + (size_t)(bn + r0) * K + cg * 8;
    const size_t rowStep64 = (size_t)64 * K;

    int aoff[4], boff[4];
#pragma unroll
    for (int mt = 0; mt < 4; ++mt) {
        int ra = wm + mt * 16 + m;
        aoff[mt] = ra * 64 + ((quad ^ (ra & 3)) * 16);
        int rb = wn + mt * 16 + m;
        boff[mt] = rb * 64 + ((quad ^ (rb & 3)) * 16);
    }

    f32x4 acc[4][4];
#pragma unroll
    for (int i = 0; i < 4; ++i)
#pragma unroll
        for (int j = 0; j < 4; ++j) acc[i][j] = (f32x4){0.f, 0.f, 0.f, 0.f};

    for (int k0 = 0; k0 < K; k0 += 32) {
        gl2lds16(gA,             AsB + wbase);
        gl2lds16(gA + rowStep64, AsB + 4096 + wbase);
        gl2lds16(gB,             BsB + wbase);
        gl2lds16(gB + rowStep64, BsB + 4096 + wbase);
        gA += 32;
        gB += 32;
        __syncthreads();

        bf16x8 af[4], bfr[4];
#pragma unroll
        for (int mt = 0; mt < 4; ++mt) af[mt]  = *(const bf16x8*)(AsB + aoff[mt]);
#pragma unroll
        for (int nt = 0; nt < 4; ++nt) bfr[nt] = *(const bf16x8*)(BsB + boff[nt]);
#pragma unroll
        for (int mt = 0; mt < 4; ++mt)
#pragma unroll
            for (int nt = 0; nt < 4; ++nt)
                acc[mt][nt] = __builtin_amdgcn_mfma_f32_16x16x32_bf16(af[mt], bfr[nt],
                                                                      acc[mt][nt], 0, 0, 0);
        __syncthreads();
    }

#pragma unroll
    for (int mt = 0; mt < 4; ++mt)
#pragma unroll
        for (int r = 0; r < 4; ++r) {
            size_t row = (size_t)(bm + wm + mt * 16 + quad * 4 + r);
#pragma unroll
            for (int nt = 0; nt < 4; ++nt) {
                int col = bn + wn + nt * 16 + m;
                float v = acc[mt][nt][r];
                if constexpr (sizeof(OutT) == 2)
                    Y[row * Nloc + col] = f2bf(v);
                else
                    Y[row * Nloc + col] = v;
            }
        }
}

__global__ __launch_bounds__(256) void qkv_gemm_bf16(const unsigned short* __restrict__ Xh,
                                                     const unsigned short* __restrict__ Wqh,
                                                     const unsigned short* __restrict__ Wkh,
                                                     const unsigned short* __restrict__ Wvh,
                                                     unsigned short* __restrict__ qh,
                                                     unsigned short* __restrict__ kh,
                                                     unsigned short* __restrict__ vh) {
    int bn0 = blockIdx.x * 128;
    const unsigned short* Wsel;
    unsigned short* Ysel;
    int bnl, Nloc;
    if (bn0 < H * D)                { Wsel = Wqh; Ysel = qh; bnl = bn0;                  Nloc = H * D;   }
    else if (bn0 < H*D + HKV*D)     { Wsel = Wkh; Ysel = kh; bnl = bn0 - H * D;          Nloc = HKV * D; }
    else                            { Wsel = Wvh; Ysel = vh; bnl = bn0 - H*D - HKV*D;    Nloc = HKV * D; }
    gemm_mfma_body<unsigned short>(Xh, Wsel, Ysel, Nloc, C, blockIdx.y * 128, bnl);
}

__global__ __launch_bounds__(256) void out_gemm_bf16(const unsigned short* __restrict__ Xh,
                                                     const unsigned short* __restrict__ Wh,
                                                     float* __restrict__ Y) {
    gemm_mfma_body<float>(Xh, Wh, Y, C, C, blockIdx.y * 128, blockIdx.x * 128);
}

// ---------------------------------------------------------------------------
// Fused RoPE in-place on bf16 q and k (q gets softmax scale * log2e folded in)
// ---------------------------------------------------------------------------
__global__ void rope_fused(unsigned short* __restrict__ qh, unsigned short* __restrict__ kh,
                           const int* __restrict__ pos_ids, float qscale) {
    int idx = blockIdx.x * blockDim.x + threadIdx.x;
    const int qtotal = B * T * H * 32;
    unsigned short* buf;
    int nheads, rel;
    float sc;
    if (idx < qtotal) { buf = qh; nheads = H;   sc = qscale; rel = idx; }
    else              { buf = kh; nheads = HKV; sc = 1.0f;   rel = idx - qtotal; }
    int d = rel & 31;
    int rest = rel >> 5;                 // = (b*T + t)*nheads + h
    int t = (rest / nheads) % T;
    float pos = (float)pos_ids[t];
    int i1 = d >> 1;
    const float NEG_LF = -(2.0f / 64.0f) * 13.287712379549449f; // -2/D * log2(10000)
    float a1 = pos * exp2f(NEG_LF * (float)i1);
    float a2 = pos * exp2f(NEG_LF * (float)(i1 + 16));
    float c1 = cosf(a1), s1 = sinf(a1);
    float c2 = cosf(a2), s2 = sinf(a2);
    size_t base = (size_t)rest * D + d;
    float x1 = bf2f(buf[base]), x2 = bf2f(buf[base + 32]);
    buf[base]      = f2bf((x1 * c1 - x2 * s1) * sc);
    buf[base + 32] = f2bf((x2 * c2 + x1 * s2) * sc);
}

// ---------------------------------------------------------------------------
// V transpose bf16 [b][t][hkv][d] -> [b][hkv][d][t]
// ---------------------------------------------------------------------------
__global__ __launch_bounds__(256) void v_transpose(const unsigned short* __restrict__ vh,
                                                   unsigned short* __restrict__ vtg) {
    __shared__ unsigned short Vs[64][72];
    const int t0 = blockIdx.x * 64;
    const int hkv = blockIdx.y;
    const int b = blockIdx.z;
    const int tid = threadIdx.x;

    for (int e = tid; e < 512; e += 256) {
        int t = e >> 3, d8 = (e & 7) * 8;
        uint4 val = *(const uint4*)(vh + ((size_t)((b * T + t0 + t) * HKV) + hkv) * D + d8);
        unsigned short tmp[8];
        *(uint4*)tmp = val;
#pragma unroll
        for (int i = 0; i < 8; ++i) Vs[d8 + i][t] = tmp[i];
    }
    __syncthreads();
    for (int e = tid; e < 512; e += 256) {
        int d = e >> 3, c = e & 7;
        *(uint4*)(vtg + ((size_t)((b * HKV + hkv) * D) + d) * T + t0 + c * 8) =
            *(const uint4*)&Vs[d][c * 8];
    }
}

// ---------------------------------------------------------------------------
// bf16 MFMA flash attention v9: v6 core (64-q blocks, gl2lds staging, cvt_pk,
// defer-rescale, setprio) with the Ps strip ALIASED into Ks:
//   P is only live between QK^T (last Ks read) and PV, so after an extra
//   lgkm-only __syncthreads the Ks buffer holds the per-wave P strips
//   (wave-private 2KB quadrants, chunk-XOR swizzled like Ks/Vt — replaces
//   the +8 pad).  LDS 25.6 -> 16.4 KB  =>  8 blocks/CU (was 6).
//   VGPR untouched (launch_bounds(256,6) keeps the R5 spill away).
// ---------------------------------------------------------------------------
__global__ __launch_bounds__(256, 6) void flash_attn_mfma(const unsigned short* __restrict__ Qh,
                                                          const unsigned short* __restrict__ Kh,
                                                          const unsigned short* __restrict__ Vtg,
                                                          unsigned short* __restrict__ Yh) {
    __shared__ __align__(16) unsigned short Ks[64 * 64];   // [key][d] -> P strips after QK^T
    __shared__ __align__(16) unsigned short Vt[64 * 64];   // [d][key], XOR-swizzled chunks

    const int q0 = ((int)gridDim.x - 1 - (int)blockIdx.x) * 64;   // heavy-first
    const int h  = blockIdx.y;
    const int b  = blockIdx.z;
    const int hkv = h >> 2;
    const int tid = threadIdx.x;
    const int wave = tid >> 6;
    const int lane = tid & 63;
    const int m = lane & 15;
    const int quad = lane >> 4;

    // Q B-frags: this wave's 16 queries q0 + wave*16 + m (resident whole kernel)
    const unsigned short* qrow = Qh + ((size_t)((b * T + q0 + wave * 16 + m) * H) + h) * D;
    const bf16x8 qa0 = *(const bf16x8*)(qrow + quad * 8);
    const bf16x8 qa1 = *(const bf16x8*)(qrow + 32 + quad * 8);

    f32x4 o[4];
#pragma unroll
    for (int dt = 0; dt < 4; ++dt) o[dt] = (f32x4){0.f, 0.f, 0.f, 0.f};
    float ms = -1e30f, ls = 0.f;

    // staging: thread t -> LDS slot t*16B (row r0=t>>3, chunk cs=t&7),
    // source chunk cg = cs ^ (r0&7)  (XOR applied on the global address)
    const int r0 = tid >> 3, cs = tid & 7, cg = cs ^ (r0 & 7);
    const int wbase = (tid & 192) * 16;
    const unsigned short* gK = Kh + ((size_t)(b * T) * HKV + hkv) * D
                                  + (size_t)r0 * (HKV * D) + cg * 8;
    const unsigned short* gV = Vtg + ((size_t)(b * HKV + hkv) * D) * (size_t)T
                                   + (size_t)r0 * T + cg * 8;
    char* KsB = (char*)Ks;
    char* VtB = (char*)Vt;

    const int qmin = q0 + wave * 16;
    // P-strip addressing inside the Ks buffer (wave-private 2KB quadrant):
    //   plain byte of key k, query m  =  m*128 + k*2 ; chunk-XOR swizzle ^ (m&7)
    const int m7 = m & 7;
    const int pwr = wave * 2048 + m * 128 + ((quad & 1) * 8);  // write base (+chunk sel per nt)
    const int qh2 = quad >> 1;
    const int prd = wave * 2048 + m * 128;                      // read base

    for (int k0 = 0; k0 <= q0; k0 += 64) {
        gl2lds16(gK,                          KsB + wbase);
        gl2lds16(gK + (size_t)32 * (HKV * D), KsB + 4096 + wbase);
        gl2lds16(gV,                          VtB + wbase);
        gl2lds16(gV + (size_t)32 * T,         VtB + 4096 + wbase);
        gK += (size_t)64 * (HKV * D);
        gV += 64;
        __syncthreads();

        // ---- S^T = K · Q^T  (4 key-tiles of 16) ----
        f32x4 s[4];
        __builtin_amdgcn_s_setprio(1);
#pragma unroll
        for (int nt = 0; nt < 4; ++nt) {
            const int kmin = k0 + nt * 16;
            if (kmin > qmin + 15) {            // fully masked tile
                s[nt] = (f32x4){-1e30f, -1e30f, -1e30f, -1e30f};
                continue;
            }
            int row = nt * 16 + m;
            const bf16x8 ka0 = *(const bf16x8*)(KsB + row * 128 + ((quad ^ (m & 7)) * 16));
            const bf16x8 ka1 = *(const bf16x8*)(KsB + row * 128 + (((quad + 4) ^ (m & 7)) * 16));
            f32x4 acc = (f32x4){0.f, 0.f, 0.f, 0.f};
            acc = __builtin_amdgcn_mfma_f32_16x16x32_bf16(ka0, qa0, acc, 0, 0, 0);
            acc = __builtin_amdgcn_mfma_f32_16x16x32_bf16(ka1, qa1, acc, 0, 0, 0);
            if (kmin + 15 > qmin) {            // diagonal: elementwise mask
                int c0 = qmin - kmin + m - 4 * quad;   // mask if r > c0
#pragma unroll
                for (int r = 0; r < 4; ++r)
                    if (r > c0) acc[r] = -1e30f;
            }
            s[nt] = acc;
        }
        __builtin_amdgcn_s_setprio(0);

        // all waves done reading Ks -> it becomes the P strip buffer
        __syncthreads();

        // ---- base-2 online softmax (lane owns query m; reduce across quads) ----
        float mx = s[0][0];
#pragma unroll
        for (int nt = 0; nt < 4; ++nt)
#pragma unroll
            for (int r = 0; r < 4; ++r) mx = fmaxf(mx, s[nt][r]);
        mx = fmaxf(mx, __shfl_xor(mx, 16));
        mx = fmaxf(mx, __shfl_xor(mx, 32));

        // defer-rescale: only pay alpha broadcast + O rescale when the running
        // max grew by more than THR (P values stay bounded by 2^THR = 256)
        float al = 1.0f;
        if (__any(mx > ms + 8.0f)) {
            float mnew = fmaxf(ms, mx);
            al = exp2f(ms - mnew);
            ms = mnew;
            float av[4];
#pragma unroll
            for (int r = 0; r < 4; ++r)
                av[r] = __shfl(al, quad * 20 + r);   // lane with m' = quad*4+r
#pragma unroll
            for (int dt = 0; dt < 4; ++dt)
#pragma unroll
                for (int r = 0; r < 4; ++r) o[dt][r] *= av[r];
        }

        float psum = 0.f;
#pragma unroll
        for (int nt = 0; nt < 4; ++nt) {
            float p0 = exp2f(s[nt][0] - ms);
            float p1 = exp2f(s[nt][1] - ms);
            float p2 = exp2f(s[nt][2] - ms);
            float p3 = exp2f(s[nt][3] - ms);
            psum += (p0 + p1) + (p2 + p3);
            uint2 w;
            w.x = cvt_pk_bf16(p0, p1);
            w.y = cvt_pk_bf16(p2, p3);
            // keys nt*16+quad*4..+3 of query m, chunk-XOR swizzled
            *(uint2*)(KsB + pwr + (((2 * nt + qh2) ^ m7) << 4)) = w;
        }
        psum += __shfl_xor(psum, 16);
        psum += __shfl_xor(psum, 32);
        ls = ls * al + psum;

        // ---- O += P · V ----
        const bf16x8 pa0 = *(const bf16x8*)(KsB + prd + ((quad ^ m7) << 4));
        const bf16x8 pa1 = *(const bf16x8*)(KsB + prd + (((quad + 4) ^ m7) << 4));
        __builtin_amdgcn_s_setprio(1);
#pragma unroll
        for (int dt = 0; dt < 4; ++dt) {
            int vrow = dt * 16 + m;
            const bf16x8 vb0 = *(const bf16x8*)(VtB + vrow * 128 + ((quad ^ (m & 7)) * 16));
            const bf16x8 vb1 = *(const bf16x8*)(VtB + vrow * 128 + (((quad + 4) ^ (m & 7)) * 16));
            o[dt] = __builtin_amdgcn_mfma_f32_16x16x32_bf16(pa0, vb0, o[dt], 0, 0, 0);
            o[dt] = __builtin_amdgcn_mfma_f32_16x16x32_bf16(pa1, vb1, o[dt], 0, 0, 0);
        }
        __builtin_amdgcn_s_setprio(0);
        __syncthreads();   // protect P strips / Vt before restage
    }

    // ---- epilogue: O / l -> bf16 y[b][t][h][d] ----
#pragma unroll
    for (int r = 0; r < 4; ++r) {
        float lv = __shfl(ls, quad * 20 + r);
        float inv = 1.0f / lv;
        int trow = q0 + wave * 16 + quad * 4 + r;
        unsigned short* yp = Yh + ((size_t)(b * T + trow) * H + h) * D;
#pragma unroll
        for (int dt = 0; dt < 4; ++dt)
            yp[dt * 16 + m] = f2bf(o[dt][r] * inv);
    }
}

// ---------------------------------------------------------------------------
extern "C" void kernel_launch(void* const* d_in, const int* in_sizes, int n_in,
                              void* d_out, int out_size, void* d_ws, size_t ws_size,
                              hipStream_t stream) {
    const float* x  = (const float*)d_in[0];
    const float* Wq = (const float*)d_in[1];
    const float* Wk = (const float*)d_in[2];
    const float* Wv = (const float*)d_in[3];
    const float* Wc = (const float*)d_in[4];
    const int*  pos = (const int*)d_in[5];
    float* out = (float*)d_out;

    unsigned short* xh  = (unsigned short*)d_ws;           // contiguous with the 4 weight
    unsigned short* wqh = xh  + (size_t)B * T * C;         // buffers — fused cast relies on it
    unsigned short* wkh = wqh + (size_t)H * D * C;
    unsigned short* wvh = wkh + (size_t)HKV * D * C;
    unsigned short* wch = wvh + (size_t)HKV * D * C;
    unsigned short* qh  = wch + (size_t)C * C;
    unsigned short* kh  = qh  + (size_t)B * T * H * D;
    unsigned short* vh  = kh  + (size_t)B * T * HKV * D;
    unsigned short* vtg = vh  + (size_t)B * T * HKV * D;
    unsigned short* yh  = xh;                              // alias (xh dead after QKV)

    // 1) fused cast fp32 -> bf16 of x + Wq + Wk + Wv + Wc (one launch)
    const size_t cast_total = (size_t)B * T * C + (size_t)(H + 2 * HKV) * D * C + (size_t)C * C;
    cast_all_bf16<<<(unsigned)(cast_total / (256 * 8)), 256, 0, stream>>>(x, Wq, Wk, Wv, Wc, xh);

    // 2) fused QKV projection (bf16 MFMA)
    dim3 g1((H * D + 2 * HKV * D) / 128, (B * T) / 128);
    qkv_gemm_bf16<<<g1, 256, 0, stream>>>(xh, wqh, wkh, wvh, qh, kh, vh);

    // 3) fused RoPE on q (scale folded) + k; V transpose
    const float QSCALE = SCALE * 1.4426950408889634f;  // SCALE * log2(e)
    rope_fused<<<(B * T * (H + HKV) * 32) / 256, 256, 0, stream>>>(qh, kh, pos, QSCALE);
    v_transpose<<<dim3(T / 64, HKV, B), 256, 0, stream>>>(vh, vtg);

    // 4) causal GQA flash attention (64-q blocks, 8 blocks/CU)
    dim3 g2(T / 64, H, B);
    flash_attn_mfma<<<g2, 256, 0, stream>>>(qh, kh, vtg, yh);

    // 5) output projection
    dim3 g3(C / 128, (B * T) / 128);
    out_gemm_bf16<<<g3, 256, 0, stream>>>(yh, wch, out);
}

// Round 7
// 332.982 us; speedup vs baseline: 1.5829x; 1.1311x over previous
//
#include <hip/hip_runtime.h>

constexpr int B   = 2;
constexpr int T   = 2048;
constexpr int C   = 2048;
constexpr int H   = 32;
constexpr int HKV = 8;
constexpr int D   = 64;
constexpr float SCALE = 0.125f; // 1/sqrt(64)

typedef __attribute__((ext_vector_type(8))) short bf16x8;
typedef __attribute__((ext_vector_type(4))) float f32x4;

__device__ __forceinline__ unsigned short f2bf(float f) {
    unsigned u = __builtin_bit_cast(unsigned, f);
    u += 0x7fff + ((u >> 16) & 1);          // round-to-nearest-even
    return (unsigned short)(u >> 16);
}
__device__ __forceinline__ float bf2f(unsigned short u) {
    unsigned v = (unsigned)u << 16;
    return __builtin_bit_cast(float, v);
}
// pack two f32 -> two bf16 in one instruction (no builtin on gfx950)
__device__ __forceinline__ unsigned cvt_pk_bf16(float lo, float hi) {
    unsigned r;
    asm("v_cvt_pk_bf16_f32 %0, %1, %2" : "=v"(r) : "v"(lo), "v"(hi));
    return r;
}

typedef __attribute__((address_space(1))) const unsigned char ga_t;
typedef __attribute__((address_space(3))) unsigned char lds_t;
__device__ __forceinline__ void gl2lds16(const void* g, void* l) {
    // 16B per lane, dest = wave-uniform base + lane*16
    __builtin_amdgcn_global_load_lds((ga_t*)g, (lds_t*)l, 16, 0, 0);
}

// ---------------------------------------------------------------------------
// Fused fp32 -> bf16 cast of x + all 4 weights (outputs contiguous in ws).
// ---------------------------------------------------------------------------
__global__ __launch_bounds__(256) void cast_all_bf16(const float* __restrict__ x,
                                                     const float* __restrict__ wq,
                                                     const float* __restrict__ wk,
                                                     const float* __restrict__ wv,
                                                     const float* __restrict__ wc,
                                                     unsigned short* __restrict__ out) {
    const size_t b0 = (size_t)B * T * C;            // x end
    const size_t b1 = b0 + (size_t)H * D * C;       // Wq end
    const size_t b2 = b1 + (size_t)HKV * D * C;     // Wk end
    const size_t b3 = b2 + (size_t)HKV * D * C;     // Wv end
    size_t i = ((size_t)blockIdx.x * 256 + threadIdx.x) * 8;
    const float* src;
    size_t off;
    if (i < b0)      { src = x;  off = i; }
    else if (i < b1) { src = wq; off = i - b0; }
    else if (i < b2) { src = wk; off = i - b1; }
    else if (i < b3) { src = wv; off = i - b2; }
    else             { src = wc; off = i - b3; }
    float4 a = *(const float4*)(src + off);
    float4 b = *(const float4*)(src + off + 4);
    uint4 r;
    r.x = (unsigned)f2bf(a.x) | ((unsigned)f2bf(a.y) << 16);
    r.y = (unsigned)f2bf(a.z) | ((unsigned)f2bf(a.w) << 16);
    r.z = (unsigned)f2bf(b.x) | ((unsigned)f2bf(b.y) << 16);
    r.w = (unsigned)f2bf(b.z) | ((unsigned)f2bf(b.w) << 16);
    *(uint4*)(out + i) = r;
}

// ---------------------------------------------------------------------------
// bf16 MFMA NT GEMM (round-3 proven, unchanged)
// ---------------------------------------------------------------------------
template <typename OutT>
__device__ __forceinline__ void gemm_mfma_body(const unsigned short* __restrict__ Xh,
                                               const unsigned short* __restrict__ Wh,
                                               OutT* __restrict__ Y,
                                               int Nloc, int K, int bm, int bn) {
    __shared__ __align__(16) unsigned short As[128 * 32];
    __shared__ __align__(16) unsigned short Bs[128 * 32];
    char* AsB = (char*)As;
    char* BsB = (char*)Bs;

    const int tid  = threadIdx.x;
    const int wave = tid >> 6, lane = tid & 63;
    const int wm = (wave >> 1) * 64, wn = (wave & 1) * 64;
    const int m = lane & 15, quad = lane >> 4;

    const int r0 = tid >> 2;
    const int cs = tid & 3;
    const int cg = cs ^ (r0 & 3);
    const int wbase = (tid & 192) * 16;

    const unsigned short* gA = Xh + (size_t)(bm + r0) * K + cg * 8;
    const unsigned short* gB = Wh + (size_t)(bn + r0) * K + cg * 8;
    const size_t rowStep64 = (size_t)64 * K;

    int aoff[4], boff[4];
#pragma unroll
    for (int mt = 0; mt < 4; ++mt) {
        int ra = wm + mt * 16 + m;
        aoff[mt] = ra * 64 + ((quad ^ (ra & 3)) * 16);
        int rb = wn + mt * 16 + m;
        boff[mt] = rb * 64 + ((quad ^ (rb & 3)) * 16);
    }

    f32x4 acc[4][4];
#pragma unroll
    for (int i = 0; i < 4; ++i)
#pragma unroll
        for (int j = 0; j < 4; ++j) acc[i][j] = (f32x4){0.f, 0.f, 0.f, 0.f};

    for (int k0 = 0; k0 < K; k0 += 32) {
        gl2lds16(gA,             AsB + wbase);
        gl2lds16(gA + rowStep64, AsB + 4096 + wbase);
        gl2lds16(gB,             BsB + wbase);
        gl2lds16(gB + rowStep64, BsB + 4096 + wbase);
        gA += 32;
        gB += 32;
        __syncthreads();

        bf16x8 af[4], bfr[4];
#pragma unroll
        for (int mt = 0; mt < 4; ++mt) af[mt]  = *(const bf16x8*)(AsB + aoff[mt]);
#pragma unroll
        for (int nt = 0; nt < 4; ++nt) bfr[nt] = *(const bf16x8*)(BsB + boff[nt]);
#pragma unroll
        for (int mt = 0; mt < 4; ++mt)
#pragma unroll
            for (int nt = 0; nt < 4; ++nt)
                acc[mt][nt] = __builtin_amdgcn_mfma_f32_16x16x32_bf16(af[mt], bfr[nt],
                                                                      acc[mt][nt], 0, 0, 0);
        __syncthreads();
    }

#pragma unroll
    for (int mt = 0; mt < 4; ++mt)
#pragma unroll
        for (int r = 0; r < 4; ++r) {
            size_t row = (size_t)(bm + wm + mt * 16 + quad * 4 + r);
#pragma unroll
            for (int nt = 0; nt < 4; ++nt) {
                int col = bn + wn + nt * 16 + m;
                float v = acc[mt][nt][r];
                if constexpr (sizeof(OutT) == 2)
                    Y[row * Nloc + col] = f2bf(v);
                else
                    Y[row * Nloc + col] = v;
            }
        }
}

__global__ __launch_bounds__(256) void qkv_gemm_bf16(const unsigned short* __restrict__ Xh,
                                                     const unsigned short* __restrict__ Wqh,
                                                     const unsigned short* __restrict__ Wkh,
                                                     const unsigned short* __restrict__ Wvh,
                                                     unsigned short* __restrict__ qh,
                                                     unsigned short* __restrict__ kh,
                                                     unsigned short* __restrict__ vh) {
    int bn0 = blockIdx.x * 128;
    const unsigned short* Wsel;
    unsigned short* Ysel;
    int bnl, Nloc;
    if (bn0 < H * D)                { Wsel = Wqh; Ysel = qh; bnl = bn0;                  Nloc = H * D;   }
    else if (bn0 < H*D + HKV*D)     { Wsel = Wkh; Ysel = kh; bnl = bn0 - H * D;          Nloc = HKV * D; }
    else                            { Wsel = Wvh; Ysel = vh; bnl = bn0 - H*D - HKV*D;    Nloc = HKV * D; }
    gemm_mfma_body<unsigned short>(Xh, Wsel, Ysel, Nloc, C, blockIdx.y * 128, bnl);
}

__global__ __launch_bounds__(256) void out_gemm_bf16(const unsigned short* __restrict__ Xh,
                                                     const unsigned short* __restrict__ Wh,
                                                     float* __restrict__ Y) {
    gemm_mfma_body<float>(Xh, Wh, Y, C, C, blockIdx.y * 128, blockIdx.x * 128);
}

// ---------------------------------------------------------------------------
// Fused RoPE in-place on bf16 q and k (q gets softmax scale * log2e folded in)
// ---------------------------------------------------------------------------
__global__ void rope_fused(unsigned short* __restrict__ qh, unsigned short* __restrict__ kh,
                           const int* __restrict__ pos_ids, float qscale) {
    int idx = blockIdx.x * blockDim.x + threadIdx.x;
    const int qtotal = B * T * H * 32;
    unsigned short* buf;
    int nheads, rel;
    float sc;
    if (idx < qtotal) { buf = qh; nheads = H;   sc = qscale; rel = idx; }
    else              { buf = kh; nheads = HKV; sc = 1.0f;   rel = idx - qtotal; }
    int d = rel & 31;
    int rest = rel >> 5;                 // = (b*T + t)*nheads + h
    int t = (rest / nheads) % T;
    float pos = (float)pos_ids[t];
    int i1 = d >> 1;
    const float NEG_LF = -(2.0f / 64.0f) * 13.287712379549449f; // -2/D * log2(10000)
    float a1 = pos * exp2f(NEG_LF * (float)i1);
    float a2 = pos * exp2f(NEG_LF * (float)(i1 + 16));
    float c1 = cosf(a1), s1 = sinf(a1);
    float c2 = cosf(a2), s2 = sinf(a2);
    size_t base = (size_t)rest * D + d;
    float x1 = bf2f(buf[base]), x2 = bf2f(buf[base + 32]);
    buf[base]      = f2bf((x1 * c1 - x2 * s1) * sc);
    buf[base + 32] = f2bf((x2 * c2 + x1 * s2) * sc);
}

// ---------------------------------------------------------------------------
// V transpose bf16 [b][t][hkv][d] -> [b][hkv][d][t]
// ---------------------------------------------------------------------------
__global__ __launch_bounds__(256) void v_transpose(const unsigned short* __restrict__ vh,
                                                   unsigned short* __restrict__ vtg) {
    __shared__ unsigned short Vs[64][72];
    const int t0 = blockIdx.x * 64;
    const int hkv = blockIdx.y;
    const int b = blockIdx.z;
    const int tid = threadIdx.x;

    for (int e = tid; e < 512; e += 256) {
        int t = e >> 3, d8 = (e & 7) * 8;
        uint4 val = *(const uint4*)(vh + ((size_t)((b * T + t0 + t) * HKV) + hkv) * D + d8);
        unsigned short tmp[8];
        *(uint4*)tmp = val;
#pragma unroll
        for (int i = 0; i < 8; ++i) Vs[d8 + i][t] = tmp[i];
    }
    __syncthreads();
    for (int e = tid; e < 512; e += 256) {
        int d = e >> 3, c = e & 7;
        *(uint4*)(vtg + ((size_t)((b * HKV + hkv) * D) + d) * T + t0 + c * 8) =
            *(const uint4*)&Vs[d][c * 8];
    }
}

// ---------------------------------------------------------------------------
// bf16 MFMA flash attention v10: v9 core (64-q tiles, gl2lds staging, cvt_pk,
// defer-rescale, setprio, P aliased into Ks -> LDS 16.4 KB) + TRIANGLE FOLD:
//   block pairi processes q-tiles {31-pairi, pairi} -> every block runs
//   exactly 33 iterations. Grid 1024 (= 4 blocks/CU), all blocks uniform,
//   no drain tail (R6 showed the 26% occupancy was light-block drain:
//   2048 triangular blocks all resident at t=0, CUs idle behind stragglers).
// ---------------------------------------------------------------------------
__global__ __launch_bounds__(256, 6) void flash_attn_mfma(const unsigned short* __restrict__ Qh,
                                                          const unsigned short* __restrict__ Kh,
                                                          const unsigned short* __restrict__ Vtg,
                                                          unsigned short* __restrict__ Yh) {
    __shared__ __align__(16) unsigned short Ks[64 * 64];   // [key][d] -> P strips after QK^T
    __shared__ __align__(16) unsigned short Vt[64 * 64];   // [d][key], XOR-swizzled chunks

    const int pairi = blockIdx.x;          // 0 .. T/128-1
    const int h  = blockIdx.y;
    const int b  = blockIdx.z;
    const int hkv = h >> 2;
    const int tid = threadIdx.x;
    const int wave = tid >> 6;
    const int lane = tid & 63;
    const int m = lane & 15;
    const int quad = lane >> 4;

    // staging: thread t -> LDS slot t*16B (row r0=t>>3, chunk cs=t&7),
    // source chunk cg = cs ^ (r0&7)  (XOR applied on the global address)
    const int r0 = tid >> 3, cs = tid & 7, cg = cs ^ (r0 & 7);
    const int wbase = (tid & 192) * 16;
    char* KsB = (char*)Ks;
    char* VtB = (char*)Vt;

    // P-strip addressing inside the Ks buffer (wave-private 2KB quadrant):
    //   plain byte of key k, query m  =  m*128 + k*2 ; chunk-XOR swizzle ^ (m&7)
    const int m7 = m & 7;
    const int pwr = wave * 2048 + m * 128 + ((quad & 1) * 8);  // write base (+chunk sel per nt)
    const int qh2 = quad >> 1;
    const int prd = wave * 2048 + m * 128;                      // read base

    const unsigned short* gKbase = Kh + ((size_t)(b * T) * HKV + hkv) * D
                                      + (size_t)r0 * (HKV * D) + cg * 8;
    const unsigned short* gVbase = Vtg + ((size_t)(b * HKV + hkv) * D) * (size_t)T
                                       + (size_t)r0 * T + cg * 8;

#pragma unroll 1
    for (int half = 0; half < 2; ++half) {
        const int qt = half ? pairi : (T / 64 - 1 - pairi);   // heavy tile, then light tile
        const int q0 = qt * 64;
        const int qmin = q0 + wave * 16;

        // Q B-frags: this wave's 16 queries q0 + wave*16 + m
        const unsigned short* qrow = Qh + ((size_t)((b * T + q0 + wave * 16 + m) * H) + h) * D;
        const bf16x8 qa0 = *(const bf16x8*)(qrow + quad * 8);
        const bf16x8 qa1 = *(const bf16x8*)(qrow + 32 + quad * 8);

        f32x4 o[4];
#pragma unroll
        for (int dt = 0; dt < 4; ++dt) o[dt] = (f32x4){0.f, 0.f, 0.f, 0.f};
        float ms = -1e30f, ls = 0.f;

        const unsigned short* gK = gKbase;
        const unsigned short* gV = gVbase;

        for (int k0 = 0; k0 <= q0; k0 += 64) {
            gl2lds16(gK,                          KsB + wbase);
            gl2lds16(gK + (size_t)32 * (HKV * D), KsB + 4096 + wbase);
            gl2lds16(gV,                          VtB + wbase);
            gl2lds16(gV + (size_t)32 * T,         VtB + 4096 + wbase);
            gK += (size_t)64 * (HKV * D);
            gV += 64;
            __syncthreads();

            // ---- S^T = K · Q^T  (4 key-tiles of 16) ----
            f32x4 s[4];
            __builtin_amdgcn_s_setprio(1);
#pragma unroll
            for (int nt = 0; nt < 4; ++nt) {
                const int kmin = k0 + nt * 16;
                if (kmin > qmin + 15) {            // fully masked tile
                    s[nt] = (f32x4){-1e30f, -1e30f, -1e30f, -1e30f};
                    continue;
                }
                int row = nt * 16 + m;
                const bf16x8 ka0 = *(const bf16x8*)(KsB + row * 128 + ((quad ^ (m & 7)) * 16));
                const bf16x8 ka1 = *(const bf16x8*)(KsB + row * 128 + (((quad + 4) ^ (m & 7)) * 16));
                f32x4 acc = (f32x4){0.f, 0.f, 0.f, 0.f};
                acc = __builtin_amdgcn_mfma_f32_16x16x32_bf16(ka0, qa0, acc, 0, 0, 0);
                acc = __builtin_amdgcn_mfma_f32_16x16x32_bf16(ka1, qa1, acc, 0, 0, 0);
                if (kmin + 15 > qmin) {            // diagonal: elementwise mask
                    int c0 = qmin - kmin + m - 4 * quad;   // mask if r > c0
#pragma unroll
                    for (int r = 0; r < 4; ++r)
                        if (r > c0) acc[r] = -1e30f;
                }
                s[nt] = acc;
            }
            __builtin_amdgcn_s_setprio(0);

            // all waves done reading Ks -> it becomes the P strip buffer
            __syncthreads();

            // ---- base-2 online softmax (lane owns query m; reduce across quads) ----
            float mx = s[0][0];
#pragma unroll
            for (int nt = 0; nt < 4; ++nt)
#pragma unroll
                for (int r = 0; r < 4; ++r) mx = fmaxf(mx, s[nt][r]);
            mx = fmaxf(mx, __shfl_xor(mx, 16));
            mx = fmaxf(mx, __shfl_xor(mx, 32));

            // defer-rescale: only pay alpha broadcast + O rescale when the running
            // max grew by more than THR (P values stay bounded by 2^THR = 256)
            float al = 1.0f;
            if (__any(mx > ms + 8.0f)) {
                float mnew = fmaxf(ms, mx);
                al = exp2f(ms - mnew);
                ms = mnew;
                float av[4];
#pragma unroll
                for (int r = 0; r < 4; ++r)
                    av[r] = __shfl(al, quad * 20 + r);   // lane with m' = quad*4+r
#pragma unroll
                for (int dt = 0; dt < 4; ++dt)
#pragma unroll
                    for (int r = 0; r < 4; ++r) o[dt][r] *= av[r];
            }

            float psum = 0.f;
#pragma unroll
            for (int nt = 0; nt < 4; ++nt) {
                float p0 = exp2f(s[nt][0] - ms);
                float p1 = exp2f(s[nt][1] - ms);
                float p2 = exp2f(s[nt][2] - ms);
                float p3 = exp2f(s[nt][3] - ms);
                psum += (p0 + p1) + (p2 + p3);
                uint2 w;
                w.x = cvt_pk_bf16(p0, p1);
                w.y = cvt_pk_bf16(p2, p3);
                // keys nt*16+quad*4..+3 of query m, chunk-XOR swizzled
                *(uint2*)(KsB + pwr + (((2 * nt + qh2) ^ m7) << 4)) = w;
            }
            psum += __shfl_xor(psum, 16);
            psum += __shfl_xor(psum, 32);
            ls = ls * al + psum;

            // ---- O += P · V ----
            const bf16x8 pa0 = *(const bf16x8*)(KsB + prd + ((quad ^ m7) << 4));
            const bf16x8 pa1 = *(const bf16x8*)(KsB + prd + (((quad + 4) ^ m7) << 4));
            __builtin_amdgcn_s_setprio(1);
#pragma unroll
            for (int dt = 0; dt < 4; ++dt) {
                int vrow = dt * 16 + m;
                const bf16x8 vb0 = *(const bf16x8*)(VtB + vrow * 128 + ((quad ^ (m & 7)) * 16));
                const bf16x8 vb1 = *(const bf16x8*)(VtB + vrow * 128 + (((quad + 4) ^ (m & 7)) * 16));
                o[dt] = __builtin_amdgcn_mfma_f32_16x16x32_bf16(pa0, vb0, o[dt], 0, 0, 0);
                o[dt] = __builtin_amdgcn_mfma_f32_16x16x32_bf16(pa1, vb1, o[dt], 0, 0, 0);
            }
            __builtin_amdgcn_s_setprio(0);
            __syncthreads();   // protect P strips / Vt before restage
        }

        // ---- epilogue: O / l -> bf16 y[b][t][h][d] ----
#pragma unroll
        for (int r = 0; r < 4; ++r) {
            float lv = __shfl(ls, quad * 20 + r);
            float inv = 1.0f / lv;
            int trow = q0 + wave * 16 + quad * 4 + r;
            unsigned short* yp = Yh + ((size_t)(b * T + trow) * H + h) * D;
#pragma unroll
            for (int dt = 0; dt < 4; ++dt)
                yp[dt * 16 + m] = f2bf(o[dt][r] * inv);
        }
    }
}

// ---------------------------------------------------------------------------
extern "C" void kernel_launch(void* const* d_in, const int* in_sizes, int n_in,
                              void* d_out, int out_size, void* d_ws, size_t ws_size,
                              hipStream_t stream) {
    const float* x  = (const float*)d_in[0];
    const float* Wq = (const float*)d_in[1];
    const float* Wk = (const float*)d_in[2];
    const float* Wv = (const float*)d_in[3];
    const float* Wc = (const float*)d_in[4];
    const int*  pos = (const int*)d_in[5];
    float* out = (float*)d_out;

    unsigned short* xh  = (unsigned short*)d_ws;           // contiguous with the 4 weight
    unsigned short* wqh = xh  + (size_t)B * T * C;         // buffers — fused cast relies on it
    unsigned short* wkh = wqh + (size_t)H * D * C;
    unsigned short* wvh = wkh + (size_t)HKV * D * C;
    unsigned short* wch = wvh + (size_t)HKV * D * C;
    unsigned short* qh  = wch + (size_t)C * C;
    unsigned short* kh  = qh  + (size_t)B * T * H * D;
    unsigned short* vh  = kh  + (size_t)B * T * HKV * D;
    unsigned short* vtg = vh  + (size_t)B * T * HKV * D;
    unsigned short* yh  = xh;                              // alias (xh dead after QKV)

    // 1) fused cast fp32 -> bf16 of x + Wq + Wk + Wv + Wc (one launch)
    const size_t cast_total = (size_t)B * T * C + (size_t)(H + 2 * HKV) * D * C + (size_t)C * C;
    cast_all_bf16<<<(unsigned)(cast_total / (256 * 8)), 256, 0, stream>>>(x, Wq, Wk, Wv, Wc, xh);

    // 2) fused QKV projection (bf16 MFMA)
    dim3 g1((H * D + 2 * HKV * D) / 128, (B * T) / 128);
    qkv_gemm_bf16<<<g1, 256, 0, stream>>>(xh, wqh, wkh, wvh, qh, kh, vh);

    // 3) fused RoPE on q (scale folded) + k; V transpose
    const float QSCALE = SCALE * 1.4426950408889634f;  // SCALE * log2(e)
    rope_fused<<<(B * T * (H + HKV) * 32) / 256, 256, 0, stream>>>(qh, kh, pos, QSCALE);
    v_transpose<<<dim3(T / 64, HKV, B), 256, 0, stream>>>(vh, vtg);

    // 4) causal GQA flash attention (triangle-folded: 1024 uniform blocks)
    dim3 g2(T / 128, H, B);
    flash_attn_mfma<<<g2, 256, 0, stream>>>(qh, kh, vtg, yh);

    // 5) output projection
    dim3 g3(C / 128, (B * T) / 128);
    out_gemm_bf16<<<g3, 256, 0, stream>>>(yh, wch, out);
}

// Round 8
// 320.736 us; speedup vs baseline: 1.6434x; 1.0382x over previous
//
#include <hip/hip_runtime.h>

constexpr int B   = 2;
constexpr int T   = 2048;
constexpr int C   = 2048;
constexpr int H   = 32;
constexpr int HKV = 8;
constexpr int D   = 64;
constexpr float SCALE = 0.125f; // 1/sqrt(64)

typedef __attribute__((ext_vector_type(8))) short bf16x8;
typedef __attribute__((ext_vector_type(4))) float f32x4;

__device__ __forceinline__ unsigned short f2bf(float f) {
    unsigned u = __builtin_bit_cast(unsigned, f);
    u += 0x7fff + ((u >> 16) & 1);          // round-to-nearest-even
    return (unsigned short)(u >> 16);
}
__device__ __forceinline__ float bf2f(unsigned short u) {
    unsigned v = (unsigned)u << 16;
    return __builtin_bit_cast(float, v);
}
// pack two f32 -> two bf16 in one instruction (no builtin on gfx950)
__device__ __forceinline__ unsigned cvt_pk_bf16(float lo, float hi) {
    unsigned r;
    asm("v_cvt_pk_bf16_f32 %0, %1, %2" : "=v"(r) : "v"(lo), "v"(hi));
    return r;
}

typedef __attribute__((address_space(1))) const unsigned char ga_t;
typedef __attribute__((address_space(3))) unsigned char lds_t;
__device__ __forceinline__ void gl2lds16(const void* g, void* l) {
    // 16B per lane, dest = wave-uniform base + lane*16
    __builtin_amdgcn_global_load_lds((ga_t*)g, (lds_t*)l, 16, 0, 0);
}

// ---------------------------------------------------------------------------
// Fused fp32 -> bf16 cast of x + all 4 weights (outputs contiguous in ws).
// ---------------------------------------------------------------------------
__global__ __launch_bounds__(256) void cast_all_bf16(const float* __restrict__ x,
                                                     const float* __restrict__ wq,
                                                     const float* __restrict__ wk,
                                                     const float* __restrict__ wv,
                                                     const float* __restrict__ wc,
                                                     unsigned short* __restrict__ out) {
    const size_t b0 = (size_t)B * T * C;            // x end
    const size_t b1 = b0 + (size_t)H * D * C;       // Wq end
    const size_t b2 = b1 + (size_t)HKV * D * C;     // Wk end
    const size_t b3 = b2 + (size_t)HKV * D * C;     // Wv end
    size_t i = ((size_t)blockIdx.x * 256 + threadIdx.x) * 8;
    const float* src;
    size_t off;
    if (i < b0)      { src = x;  off = i; }
    else if (i < b1) { src = wq; off = i - b0; }
    else if (i < b2) { src = wk; off = i - b1; }
    else if (i < b3) { src = wv; off = i - b2; }
    else             { src = wc; off = i - b3; }
    float4 a = *(const float4*)(src + off);
    float4 b = *(const float4*)(src + off + 4);
    uint4 r;
    r.x = (unsigned)f2bf(a.x) | ((unsigned)f2bf(a.y) << 16);
    r.y = (unsigned)f2bf(a.z) | ((unsigned)f2bf(a.w) << 16);
    r.z = (unsigned)f2bf(b.x) | ((unsigned)f2bf(b.y) << 16);
    r.w = (unsigned)f2bf(b.z) | ((unsigned)f2bf(b.w) << 16);
    *(uint4*)(out + i) = r;
}

// ---------------------------------------------------------------------------
// bf16 MFMA NT GEMM — BK=64 (R8): halved barrier count per K-element vs the
// proven BK=32 body. LDS 32 KB (occupancy grid-limited at 3 blocks/CU, so no
// cliff; m132's BK=128 failure was the 64 KB LDS -> 2 blocks/CU).
// 8-chunk XOR swizzle (same pre-swizzled-global scheme, &7 instead of &3).
// ---------------------------------------------------------------------------
template <typename OutT>
__device__ __forceinline__ void gemm_mfma_body(const unsigned short* __restrict__ Xh,
                                               const unsigned short* __restrict__ Wh,
                                               OutT* __restrict__ Y,
                                               int Nloc, int K, int bm, int bn) {
    __shared__ __align__(16) unsigned short As[128 * 64];
    __shared__ __align__(16) unsigned short Bs[128 * 64];
    char* AsB = (char*)As;
    char* BsB = (char*)Bs;

    const int tid  = threadIdx.x;
    const int wave = tid >> 6, lane = tid & 63;
    const int wm = (wave >> 1) * 64, wn = (wave & 1) * 64;
    const int m = lane & 15, quad = lane >> 4;

    // staging: thread t -> LDS slot t*16B (+ call*4KB); row r0 = t>>3 (+32/call),
    // chunk slot cs = t&7, source chunk cg = cs ^ (r0&7) (pre-swizzled global)
    const int r0 = tid >> 3;
    const int cs = tid & 7;
    const int cg = cs ^ (r0 & 7);
    const int ldst = tid * 16;

    const unsigned short* gA = Xh + (size_t)(bm + r0) * K + cg * 8;
    const unsigned short* gB = Wh + (size_t)(bn + r0) * K + cg * 8;
    const size_t rowStep32 = (size_t)32 * K;

    // frag LDS offsets: row ra, logical chunk kk*4+quad -> slot chunk ^ (ra&7)
    int aoff[4][2], boff[4][2];
#pragma unroll
    for (int mt = 0; mt < 4; ++mt)
#pragma unroll
        for (int kk = 0; kk < 2; ++kk) {
            int ra = wm + mt * 16 + m;
            aoff[mt][kk] = ra * 128 + ((((kk * 4 + quad) ^ (ra & 7))) << 4);
            int rb = wn + mt * 16 + m;
            boff[mt][kk] = rb * 128 + ((((kk * 4 + quad) ^ (rb & 7))) << 4);
        }

    f32x4 acc[4][4];
#pragma unroll
    for (int i = 0; i < 4; ++i)
#pragma unroll
        for (int j = 0; j < 4; ++j) acc[i][j] = (f32x4){0.f, 0.f, 0.f, 0.f};

    for (int k0 = 0; k0 < K; k0 += 64) {
        gl2lds16(gA,                 AsB + ldst);
        gl2lds16(gA +     rowStep32, AsB +  4096 + ldst);
        gl2lds16(gA + 2 * rowStep32, AsB +  8192 + ldst);
        gl2lds16(gA + 3 * rowStep32, AsB + 12288 + ldst);
        gl2lds16(gB,                 BsB + ldst);
        gl2lds16(gB +     rowStep32, BsB +  4096 + ldst);
        gl2lds16(gB + 2 * rowStep32, BsB +  8192 + ldst);
        gl2lds16(gB + 3 * rowStep32, BsB + 12288 + ldst);
        gA += 64;
        gB += 64;
        __syncthreads();

#pragma unroll
        for (int kk = 0; kk < 2; ++kk) {
            bf16x8 af[4], bfr[4];
#pragma unroll
            for (int mt = 0; mt < 4; ++mt) af[mt]  = *(const bf16x8*)(AsB + aoff[mt][kk]);
#pragma unroll
            for (int nt = 0; nt < 4; ++nt) bfr[nt] = *(const bf16x8*)(BsB + boff[nt][kk]);
#pragma unroll
            for (int mt = 0; mt < 4; ++mt)
#pragma unroll
                for (int nt = 0; nt < 4; ++nt)
                    acc[mt][nt] = __builtin_amdgcn_mfma_f32_16x16x32_bf16(af[mt], bfr[nt],
                                                                          acc[mt][nt], 0, 0, 0);
        }
        __syncthreads();
    }

#pragma unroll
    for (int mt = 0; mt < 4; ++mt)
#pragma unroll
        for (int r = 0; r < 4; ++r) {
            size_t row = (size_t)(bm + wm + mt * 16 + quad * 4 + r);
#pragma unroll
            for (int nt = 0; nt < 4; ++nt) {
                int col = bn + wn + nt * 16 + m;
                float v = acc[mt][nt][r];
                if constexpr (sizeof(OutT) == 2)
                    Y[row * Nloc + col] = f2bf(v);
                else
                    Y[row * Nloc + col] = v;
            }
        }
}

__global__ __launch_bounds__(256) void qkv_gemm_bf16(const unsigned short* __restrict__ Xh,
                                                     const unsigned short* __restrict__ Wqh,
                                                     const unsigned short* __restrict__ Wkh,
                                                     const unsigned short* __restrict__ Wvh,
                                                     unsigned short* __restrict__ qh,
                                                     unsigned short* __restrict__ kh,
                                                     unsigned short* __restrict__ vh) {
    int bn0 = blockIdx.x * 128;
    const unsigned short* Wsel;
    unsigned short* Ysel;
    int bnl, Nloc;
    if (bn0 < H * D)                { Wsel = Wqh; Ysel = qh; bnl = bn0;                  Nloc = H * D;   }
    else if (bn0 < H*D + HKV*D)     { Wsel = Wkh; Ysel = kh; bnl = bn0 - H * D;          Nloc = HKV * D; }
    else                            { Wsel = Wvh; Ysel = vh; bnl = bn0 - H*D - HKV*D;    Nloc = HKV * D; }
    gemm_mfma_body<unsigned short>(Xh, Wsel, Ysel, Nloc, C, blockIdx.y * 128, bnl);
}

__global__ __launch_bounds__(256) void out_gemm_bf16(const unsigned short* __restrict__ Xh,
                                                     const unsigned short* __restrict__ Wh,
                                                     float* __restrict__ Y) {
    gemm_mfma_body<float>(Xh, Wh, Y, C, C, blockIdx.y * 128, blockIdx.x * 128);
}

// ---------------------------------------------------------------------------
// Fused RoPE in-place on bf16 q and k (q gets softmax scale * log2e folded in)
// ---------------------------------------------------------------------------
__global__ void rope_fused(unsigned short* __restrict__ qh, unsigned short* __restrict__ kh,
                           const int* __restrict__ pos_ids, float qscale) {
    int idx = blockIdx.x * blockDim.x + threadIdx.x;
    const int qtotal = B * T * H * 32;
    unsigned short* buf;
    int nheads, rel;
    float sc;
    if (idx < qtotal) { buf = qh; nheads = H;   sc = qscale; rel = idx; }
    else              { buf = kh; nheads = HKV; sc = 1.0f;   rel = idx - qtotal; }
    int d = rel & 31;
    int rest = rel >> 5;                 // = (b*T + t)*nheads + h
    int t = (rest / nheads) % T;
    float pos = (float)pos_ids[t];
    int i1 = d >> 1;
    const float NEG_LF = -(2.0f / 64.0f) * 13.287712379549449f; // -2/D * log2(10000)
    float a1 = pos * exp2f(NEG_LF * (float)i1);
    float a2 = pos * exp2f(NEG_LF * (float)(i1 + 16));
    float c1 = cosf(a1), s1 = sinf(a1);
    float c2 = cosf(a2), s2 = sinf(a2);
    size_t base = (size_t)rest * D + d;
    float x1 = bf2f(buf[base]), x2 = bf2f(buf[base + 32]);
    buf[base]      = f2bf((x1 * c1 - x2 * s1) * sc);
    buf[base + 32] = f2bf((x2 * c2 + x1 * s2) * sc);
}

// ---------------------------------------------------------------------------
// V transpose bf16 [b][t][hkv][d] -> [b][hkv][d][t]
// ---------------------------------------------------------------------------
__global__ __launch_bounds__(256) void v_transpose(const unsigned short* __restrict__ vh,
                                                   unsigned short* __restrict__ vtg) {
    __shared__ unsigned short Vs[64][72];
    const int t0 = blockIdx.x * 64;
    const int hkv = blockIdx.y;
    const int b = blockIdx.z;
    const int tid = threadIdx.x;

    for (int e = tid; e < 512; e += 256) {
        int t = e >> 3, d8 = (e & 7) * 8;
        uint4 val = *(const uint4*)(vh + ((size_t)((b * T + t0 + t) * HKV) + hkv) * D + d8);
        unsigned short tmp[8];
        *(uint4*)tmp = val;
#pragma unroll
        for (int i = 0; i < 8; ++i) Vs[d8 + i][t] = tmp[i];
    }
    __syncthreads();
    for (int e = tid; e < 512; e += 256) {
        int d = e >> 3, c = e & 7;
        *(uint4*)(vtg + ((size_t)((b * HKV + hkv) * D) + d) * T + t0 + c * 8) =
            *(const uint4*)&Vs[d][c * 8];
    }
}

// ---------------------------------------------------------------------------
// bf16 MFMA flash attention v11: v10 (triangle-folded, P aliased into Ks,
// cvt_pk, defer-rescale, setprio) with the register budget RELAXED:
// __launch_bounds__(256,4) instead of (256,6). Grid is 1024 = exactly
// 4 blocks/CU, so the 6-block bound bought nothing — but its 40-VGPR squeeze
// forced the compiler to rematerialize the 16 loop-invariant XOR'd LDS frag
// addresses every iteration (VALU chain). 128-VGPR budget lets them hoist.
// ---------------------------------------------------------------------------
__global__ __launch_bounds__(256, 4) void flash_attn_mfma(const unsigned short* __restrict__ Qh,
                                                          const unsigned short* __restrict__ Kh,
                                                          const unsigned short* __restrict__ Vtg,
                                                          unsigned short* __restrict__ Yh) {
    __shared__ __align__(16) unsigned short Ks[64 * 64];   // [key][d] -> P strips after QK^T
    __shared__ __align__(16) unsigned short Vt[64 * 64];   // [d][key], XOR-swizzled chunks

    const int pairi = blockIdx.x;          // 0 .. T/128-1
    const int h  = blockIdx.y;
    const int b  = blockIdx.z;
    const int hkv = h >> 2;
    const int tid = threadIdx.x;
    const int wave = tid >> 6;
    const int lane = tid & 63;
    const int m = lane & 15;
    const int quad = lane >> 4;

    // staging: thread t -> LDS slot t*16B (row r0=t>>3, chunk cs=t&7),
    // source chunk cg = cs ^ (r0&7)  (XOR applied on the global address)
    const int r0 = tid >> 3, cs = tid & 7, cg = cs ^ (r0 & 7);
    const int wbase = (tid & 192) * 16;
    char* KsB = (char*)Ks;
    char* VtB = (char*)Vt;

    // P-strip addressing inside the Ks buffer (wave-private 2KB quadrant):
    //   plain byte of key k, query m  =  m*128 + k*2 ; chunk-XOR swizzle ^ (m&7)
    const int m7 = m & 7;
    const int pwr = wave * 2048 + m * 128 + ((quad & 1) * 8);  // write base (+chunk sel per nt)
    const int qh2 = quad >> 1;
    const int prd = wave * 2048 + m * 128;                      // read base

    const unsigned short* gKbase = Kh + ((size_t)(b * T) * HKV + hkv) * D
                                      + (size_t)r0 * (HKV * D) + cg * 8;
    const unsigned short* gVbase = Vtg + ((size_t)(b * HKV + hkv) * D) * (size_t)T
                                       + (size_t)r0 * T + cg * 8;

#pragma unroll 1
    for (int half = 0; half < 2; ++half) {
        const int qt = half ? pairi : (T / 64 - 1 - pairi);   // heavy tile, then light tile
        const int q0 = qt * 64;
        const int qmin = q0 + wave * 16;

        // Q B-frags: this wave's 16 queries q0 + wave*16 + m
        const unsigned short* qrow = Qh + ((size_t)((b * T + q0 + wave * 16 + m) * H) + h) * D;
        const bf16x8 qa0 = *(const bf16x8*)(qrow + quad * 8);
        const bf16x8 qa1 = *(const bf16x8*)(qrow + 32 + quad * 8);

        f32x4 o[4];
#pragma unroll
        for (int dt = 0; dt < 4; ++dt) o[dt] = (f32x4){0.f, 0.f, 0.f, 0.f};
        float ms = -1e30f, ls = 0.f;

        const unsigned short* gK = gKbase;
        const unsigned short* gV = gVbase;

        for (int k0 = 0; k0 <= q0; k0 += 64) {
            gl2lds16(gK,                          KsB + wbase);
            gl2lds16(gK + (size_t)32 * (HKV * D), KsB + 4096 + wbase);
            gl2lds16(gV,                          VtB + wbase);
            gl2lds16(gV + (size_t)32 * T,         VtB + 4096 + wbase);
            gK += (size_t)64 * (HKV * D);
            gV += 64;
            __syncthreads();

            // ---- S^T = K · Q^T  (4 key-tiles of 16) ----
            f32x4 s[4];
            __builtin_amdgcn_s_setprio(1);
#pragma unroll
            for (int nt = 0; nt < 4; ++nt) {
                const int kmin = k0 + nt * 16;
                if (kmin > qmin + 15) {            // fully masked tile
                    s[nt] = (f32x4){-1e30f, -1e30f, -1e30f, -1e30f};
                    continue;
                }
                int row = nt * 16 + m;
                const bf16x8 ka0 = *(const bf16x8*)(KsB + row * 128 + ((quad ^ (m & 7)) * 16));
                const bf16x8 ka1 = *(const bf16x8*)(KsB + row * 128 + (((quad + 4) ^ (m & 7)) * 16));
                f32x4 acc = (f32x4){0.f, 0.f, 0.f, 0.f};
                acc = __builtin_amdgcn_mfma_f32_16x16x32_bf16(ka0, qa0, acc, 0, 0, 0);
                acc = __builtin_amdgcn_mfma_f32_16x16x32_bf16(ka1, qa1, acc, 0, 0, 0);
                if (kmin + 15 > qmin) {            // diagonal: elementwise mask
                    int c0 = qmin - kmin + m - 4 * quad;   // mask if r > c0
#pragma unroll
                    for (int r = 0; r < 4; ++r)
                        if (r > c0) acc[r] = -1e30f;
                }
                s[nt] = acc;
            }
            __builtin_amdgcn_s_setprio(0);

            // all waves done reading Ks -> it becomes the P strip buffer
            __syncthreads();

            // ---- base-2 online softmax (lane owns query m; reduce across quads) ----
            float mx = s[0][0];
#pragma unroll
            for (int nt = 0; nt < 4; ++nt)
#pragma unroll
                for (int r = 0; r < 4; ++r) mx = fmaxf(mx, s[nt][r]);
            mx = fmaxf(mx, __shfl_xor(mx, 16));
            mx = fmaxf(mx, __shfl_xor(mx, 32));

            // defer-rescale: only pay alpha broadcast + O rescale when the running
            // max grew by more than THR (P values stay bounded by 2^THR = 256)
            float al = 1.0f;
            if (__any(mx > ms + 8.0f)) {
                float mnew = fmaxf(ms, mx);
                al = exp2f(ms - mnew);
                ms = mnew;
                float av[4];
#pragma unroll
                for (int r = 0; r < 4; ++r)
                    av[r] = __shfl(al, quad * 20 + r);   // lane with m' = quad*4+r
#pragma unroll
                for (int dt = 0; dt < 4; ++dt)
#pragma unroll
                    for (int r = 0; r < 4; ++r) o[dt][r] *= av[r];
            }

            float psum = 0.f;
#pragma unroll
            for (int nt = 0; nt < 4; ++nt) {
                float p0 = exp2f(s[nt][0] - ms);
                float p1 = exp2f(s[nt][1] - ms);
                float p2 = exp2f(s[nt][2] - ms);
                float p3 = exp2f(s[nt][3] - ms);
                psum += (p0 + p1) + (p2 + p3);
                uint2 w;
                w.x = cvt_pk_bf16(p0, p1);
                w.y = cvt_pk_bf16(p2, p3);
                // keys nt*16+quad*4..+3 of query m, chunk-XOR swizzled
                *(uint2*)(KsB + pwr + (((2 * nt + qh2) ^ m7) << 4)) = w;
            }
            psum += __shfl_xor(psum, 16);
            psum += __shfl_xor(psum, 32);
            ls = ls * al + psum;

            // ---- O += P · V ----
            const bf16x8 pa0 = *(const bf16x8*)(KsB + prd + ((quad ^ m7) << 4));
            const bf16x8 pa1 = *(const bf16x8*)(KsB + prd + (((quad + 4) ^ m7) << 4));
            __builtin_amdgcn_s_setprio(1);
#pragma unroll
            for (int dt = 0; dt < 4; ++dt) {
                int vrow = dt * 16 + m;
                const bf16x8 vb0 = *(const bf16x8*)(VtB + vrow * 128 + ((quad ^ (m & 7)) * 16));
                const bf16x8 vb1 = *(const bf16x8*)(VtB + vrow * 128 + (((quad + 4) ^ (m & 7)) * 16));
                o[dt] = __builtin_amdgcn_mfma_f32_16x16x32_bf16(pa0, vb0, o[dt], 0, 0, 0);
                o[dt] = __builtin_amdgcn_mfma_f32_16x16x32_bf16(pa1, vb1, o[dt], 0, 0, 0);
            }
            __builtin_amdgcn_s_setprio(0);
            __syncthreads();   // protect P strips / Vt before restage
        }

        // ---- epilogue: O / l -> bf16 y[b][t][h][d] ----
#pragma unroll
        for (int r = 0; r < 4; ++r) {
            float lv = __shfl(ls, quad * 20 + r);
            float inv = 1.0f / lv;
            int trow = q0 + wave * 16 + quad * 4 + r;
            unsigned short* yp = Yh + ((size_t)(b * T + trow) * H + h) * D;
#pragma unroll
            for (int dt = 0; dt < 4; ++dt)
                yp[dt * 16 + m] = f2bf(o[dt][r] * inv);
        }
    }
}

// ---------------------------------------------------------------------------
extern "C" void kernel_launch(void* const* d_in, const int* in_sizes, int n_in,
                              void* d_out, int out_size, void* d_ws, size_t ws_size,
                              hipStream_t stream) {
    const float* x  = (const float*)d_in[0];
    const float* Wq = (const float*)d_in[1];
    const float* Wk = (const float*)d_in[2];
    const float* Wv = (const float*)d_in[3];
    const float* Wc = (const float*)d_in[4];
    const int*  pos = (const int*)d_in[5];
    float* out = (float*)d_out;

    unsigned short* xh  = (unsigned short*)d_ws;           // contiguous with the 4 weight
    unsigned short* wqh = xh  + (size_t)B * T * C;         // buffers — fused cast relies on it
    unsigned short* wkh = wqh + (size_t)H * D * C;
    unsigned short* wvh = wkh + (size_t)HKV * D * C;
    unsigned short* wch = wvh + (size_t)HKV * D * C;
    unsigned short* qh  = wch + (size_t)C * C;
    unsigned short* kh  = qh  + (size_t)B * T * H * D;
    unsigned short* vh  = kh  + (size_t)B * T * HKV * D;
    unsigned short* vtg = vh  + (size_t)B * T * HKV * D;
    unsigned short* yh  = xh;                              // alias (xh dead after QKV)

    // 1) fused cast fp32 -> bf16 of x + Wq + Wk + Wv + Wc (one launch)
    const size_t cast_total = (size_t)B * T * C + (size_t)(H + 2 * HKV) * D * C + (size_t)C * C;
    cast_all_bf16<<<(unsigned)(cast_total / (256 * 8)), 256, 0, stream>>>(x, Wq, Wk, Wv, Wc, xh);

    // 2) fused QKV projection (bf16 MFMA, BK=64)
    dim3 g1((H * D + 2 * HKV * D) / 128, (B * T) / 128);
    qkv_gemm_bf16<<<g1, 256, 0, stream>>>(xh, wqh, wkh, wvh, qh, kh, vh);

    // 3) fused RoPE on q (scale folded) + k; V transpose
    const float QSCALE = SCALE * 1.4426950408889634f;  // SCALE * log2(e)
    rope_fused<<<(B * T * (H + HKV) * 32) / 256, 256, 0, stream>>>(qh, kh, pos, QSCALE);
    v_transpose<<<dim3(T / 64, HKV, B), 256, 0, stream>>>(vh, vtg);

    // 4) causal GQA flash attention (triangle-folded: 1024 uniform blocks)
    dim3 g2(T / 128, H, B);
    flash_attn_mfma<<<g2, 256, 0, stream>>>(qh, kh, vtg, yh);

    // 5) output projection (BK=64)
    dim3 g3(C / 128, (B * T) / 128);
    out_gemm_bf16<<<g3, 256, 0, stream>>>(yh, wch, out);
}

// Round 9
// 315.536 us; speedup vs baseline: 1.6705x; 1.0165x over previous
//
#include <hip/hip_runtime.h>

constexpr int B   = 2;
constexpr int T   = 2048;
constexpr int C   = 2048;
constexpr int H   = 32;
constexpr int HKV = 8;
constexpr int D   = 64;
constexpr float SCALE = 0.125f; // 1/sqrt(64)

typedef __attribute__((ext_vector_type(8))) short bf16x8;
typedef __attribute__((ext_vector_type(4))) float f32x4;

__device__ __forceinline__ unsigned short f2bf(float f) {
    unsigned u = __builtin_bit_cast(unsigned, f);
    u += 0x7fff + ((u >> 16) & 1);          // round-to-nearest-even
    return (unsigned short)(u >> 16);
}
__device__ __forceinline__ float bf2f(unsigned short u) {
    unsigned v = (unsigned)u << 16;
    return __builtin_bit_cast(float, v);
}
// pack two f32 -> two bf16 in one instruction (no builtin on gfx950)
__device__ __forceinline__ unsigned cvt_pk_bf16(float lo, float hi) {
    unsigned r;
    asm("v_cvt_pk_bf16_f32 %0, %1, %2" : "=v"(r) : "v"(lo), "v"(hi));
    return r;
}

typedef __attribute__((address_space(1))) const unsigned char ga_t;
typedef __attribute__((address_space(3))) unsigned char lds_t;
__device__ __forceinline__ void gl2lds16(const void* g, void* l) {
    // 16B per lane, dest = wave-uniform base + lane*16
    __builtin_amdgcn_global_load_lds((ga_t*)g, (lds_t*)l, 16, 0, 0);
}

// ---------------------------------------------------------------------------
// Fused fp32 -> bf16 cast of x + all 4 weights (outputs contiguous in ws).
// ---------------------------------------------------------------------------
__global__ __launch_bounds__(256) void cast_all_bf16(const float* __restrict__ x,
                                                     const float* __restrict__ wq,
                                                     const float* __restrict__ wk,
                                                     const float* __restrict__ wv,
                                                     const float* __restrict__ wc,
                                                     unsigned short* __restrict__ out) {
    const size_t b0 = (size_t)B * T * C;            // x end
    const size_t b1 = b0 + (size_t)H * D * C;       // Wq end
    const size_t b2 = b1 + (size_t)HKV * D * C;     // Wk end
    const size_t b3 = b2 + (size_t)HKV * D * C;     // Wv end
    size_t i = ((size_t)blockIdx.x * 256 + threadIdx.x) * 8;
    const float* src;
    size_t off;
    if (i < b0)      { src = x;  off = i; }
    else if (i < b1) { src = wq; off = i - b0; }
    else if (i < b2) { src = wk; off = i - b1; }
    else if (i < b3) { src = wv; off = i - b2; }
    else             { src = wc; off = i - b3; }
    float4 a = *(const float4*)(src + off);
    float4 b = *(const float4*)(src + off + 4);
    uint4 r;
    r.x = (unsigned)f2bf(a.x) | ((unsigned)f2bf(a.y) << 16);
    r.y = (unsigned)f2bf(a.z) | ((unsigned)f2bf(a.w) << 16);
    r.z = (unsigned)f2bf(b.x) | ((unsigned)f2bf(b.y) << 16);
    r.w = (unsigned)f2bf(b.z) | ((unsigned)f2bf(b.w) << 16);
    *(uint4*)(out + i) = r;
}

// ---------------------------------------------------------------------------
// bf16 MFMA NT GEMM — BK=64 (R8-proven): halved barrier count per K-element.
// LDS 32 KB, 8-chunk XOR swizzle via pre-swizzled global source.
// ---------------------------------------------------------------------------
template <typename OutT>
__device__ __forceinline__ void gemm_mfma_body(const unsigned short* __restrict__ Xh,
                                               const unsigned short* __restrict__ Wh,
                                               OutT* __restrict__ Y,
                                               int Nloc, int K, int bm, int bn) {
    __shared__ __align__(16) unsigned short As[128 * 64];
    __shared__ __align__(16) unsigned short Bs[128 * 64];
    char* AsB = (char*)As;
    char* BsB = (char*)Bs;

    const int tid  = threadIdx.x;
    const int wave = tid >> 6, lane = tid & 63;
    const int wm = (wave >> 1) * 64, wn = (wave & 1) * 64;
    const int m = lane & 15, quad = lane >> 4;

    // staging: thread t -> LDS slot t*16B (+ call*4KB); row r0 = t>>3 (+32/call),
    // chunk slot cs = t&7, source chunk cg = cs ^ (r0&7) (pre-swizzled global)
    const int r0 = tid >> 3;
    const int cs = tid & 7;
    const int cg = cs ^ (r0 & 7);
    const int ldst = tid * 16;

    const unsigned short* gA = Xh + (size_t)(bm + r0) * K + cg * 8;
    const unsigned short* gB = Wh + (size_t)(bn + r0) * K + cg * 8;
    const size_t rowStep32 = (size_t)32 * K;

    // frag LDS offsets: row ra, logical chunk kk*4+quad -> slot chunk ^ (ra&7)
    int aoff[4][2], boff[4][2];
#pragma unroll
    for (int mt = 0; mt < 4; ++mt)
#pragma unroll
        for (int kk = 0; kk < 2; ++kk) {
            int ra = wm + mt * 16 + m;
            aoff[mt][kk] = ra * 128 + ((((kk * 4 + quad) ^ (ra & 7))) << 4);
            int rb = wn + mt * 16 + m;
            boff[mt][kk] = rb * 128 + ((((kk * 4 + quad) ^ (rb & 7))) << 4);
        }

    f32x4 acc[4][4];
#pragma unroll
    for (int i = 0; i < 4; ++i)
#pragma unroll
        for (int j = 0; j < 4; ++j) acc[i][j] = (f32x4){0.f, 0.f, 0.f, 0.f};

    for (int k0 = 0; k0 < K; k0 += 64) {
        gl2lds16(gA,                 AsB + ldst);
        gl2lds16(gA +     rowStep32, AsB +  4096 + ldst);
        gl2lds16(gA + 2 * rowStep32, AsB +  8192 + ldst);
        gl2lds16(gA + 3 * rowStep32, AsB + 12288 + ldst);
        gl2lds16(gB,                 BsB + ldst);
        gl2lds16(gB +     rowStep32, BsB +  4096 + ldst);
        gl2lds16(gB + 2 * rowStep32, BsB +  8192 + ldst);
        gl2lds16(gB + 3 * rowStep32, BsB + 12288 + ldst);
        gA += 64;
        gB += 64;
        __syncthreads();

#pragma unroll
        for (int kk = 0; kk < 2; ++kk) {
            bf16x8 af[4], bfr[4];
#pragma unroll
            for (int mt = 0; mt < 4; ++mt) af[mt]  = *(const bf16x8*)(AsB + aoff[mt][kk]);
#pragma unroll
            for (int nt = 0; nt < 4; ++nt) bfr[nt] = *(const bf16x8*)(BsB + boff[nt][kk]);
#pragma unroll
            for (int mt = 0; mt < 4; ++mt)
#pragma unroll
                for (int nt = 0; nt < 4; ++nt)
                    acc[mt][nt] = __builtin_amdgcn_mfma_f32_16x16x32_bf16(af[mt], bfr[nt],
                                                                          acc[mt][nt], 0, 0, 0);
        }
        __syncthreads();
    }

#pragma unroll
    for (int mt = 0; mt < 4; ++mt)
#pragma unroll
        for (int r = 0; r < 4; ++r) {
            size_t row = (size_t)(bm + wm + mt * 16 + quad * 4 + r);
#pragma unroll
            for (int nt = 0; nt < 4; ++nt) {
                int col = bn + wn + nt * 16 + m;
                float v = acc[mt][nt][r];
                if constexpr (sizeof(OutT) == 2)
                    Y[row * Nloc + col] = f2bf(v);
                else
                    Y[row * Nloc + col] = v;
            }
        }
}

__global__ __launch_bounds__(256) void qkv_gemm_bf16(const unsigned short* __restrict__ Xh,
                                                     const unsigned short* __restrict__ Wqh,
                                                     const unsigned short* __restrict__ Wkh,
                                                     const unsigned short* __restrict__ Wvh,
                                                     unsigned short* __restrict__ qh,
                                                     unsigned short* __restrict__ kh,
                                                     unsigned short* __restrict__ vh) {
    int bn0 = blockIdx.x * 128;
    const unsigned short* Wsel;
    unsigned short* Ysel;
    int bnl, Nloc;
    if (bn0 < H * D)                { Wsel = Wqh; Ysel = qh; bnl = bn0;                  Nloc = H * D;   }
    else if (bn0 < H*D + HKV*D)     { Wsel = Wkh; Ysel = kh; bnl = bn0 - H * D;          Nloc = HKV * D; }
    else                            { Wsel = Wvh; Ysel = vh; bnl = bn0 - H*D - HKV*D;    Nloc = HKV * D; }
    gemm_mfma_body<unsigned short>(Xh, Wsel, Ysel, Nloc, C, blockIdx.y * 128, bnl);
}

__global__ __launch_bounds__(256) void out_gemm_bf16(const unsigned short* __restrict__ Xh,
                                                     const unsigned short* __restrict__ Wh,
                                                     float* __restrict__ Y) {
    gemm_mfma_body<float>(Xh, Wh, Y, C, C, blockIdx.y * 128, blockIdx.x * 128);
}

// ---------------------------------------------------------------------------
// Fused RoPE in-place on bf16 q and k (q gets softmax scale * log2e folded in)
// ---------------------------------------------------------------------------
__global__ void rope_fused(unsigned short* __restrict__ qh, unsigned short* __restrict__ kh,
                           const int* __restrict__ pos_ids, float qscale) {
    int idx = blockIdx.x * blockDim.x + threadIdx.x;
    const int qtotal = B * T * H * 32;
    unsigned short* buf;
    int nheads, rel;
    float sc;
    if (idx < qtotal) { buf = qh; nheads = H;   sc = qscale; rel = idx; }
    else              { buf = kh; nheads = HKV; sc = 1.0f;   rel = idx - qtotal; }
    int d = rel & 31;
    int rest = rel >> 5;                 // = (b*T + t)*nheads + h
    int t = (rest / nheads) % T;
    float pos = (float)pos_ids[t];
    int i1 = d >> 1;
    const float NEG_LF = -(2.0f / 64.0f) * 13.287712379549449f; // -2/D * log2(10000)
    float a1 = pos * exp2f(NEG_LF * (float)i1);
    float a2 = pos * exp2f(NEG_LF * (float)(i1 + 16));
    float c1 = cosf(a1), s1 = sinf(a1);
    float c2 = cosf(a2), s2 = sinf(a2);
    size_t base = (size_t)rest * D + d;
    float x1 = bf2f(buf[base]), x2 = bf2f(buf[base + 32]);
    buf[base]      = f2bf((x1 * c1 - x2 * s1) * sc);
    buf[base + 32] = f2bf((x2 * c2 + x1 * s2) * sc);
}

// ---------------------------------------------------------------------------
// V transpose bf16 [b][t][hkv][d] -> [b][hkv][d][t]
// ---------------------------------------------------------------------------
__global__ __launch_bounds__(256) void v_transpose(const unsigned short* __restrict__ vh,
                                                   unsigned short* __restrict__ vtg) {
    __shared__ unsigned short Vs[64][72];
    const int t0 = blockIdx.x * 64;
    const int hkv = blockIdx.y;
    const int b = blockIdx.z;
    const int tid = threadIdx.x;

    for (int e = tid; e < 512; e += 256) {
        int t = e >> 3, d8 = (e & 7) * 8;
        uint4 val = *(const uint4*)(vh + ((size_t)((b * T + t0 + t) * HKV) + hkv) * D + d8);
        unsigned short tmp[8];
        *(uint4*)tmp = val;
#pragma unroll
        for (int i = 0; i < 8; ++i) Vs[d8 + i][t] = tmp[i];
    }
    __syncthreads();
    for (int e = tid; e < 512; e += 256) {
        int d = e >> 3, c = e & 7;
        *(uint4*)(vtg + ((size_t)((b * HKV + hkv) * D) + d) * T + t0 + c * 8) =
            *(const uint4*)&Vs[d][c * 8];
    }
}

// ---------------------------------------------------------------------------
// bf16 MFMA flash attention v12: v11 core (triangle-folded, P aliased into
// current Ks half, cvt_pk, defer-rescale, setprio) + DOUBLE-BUFFERED K/V:
//   gl2lds of tile t+1 into buf^1 is issued at the TOP of iteration t, so
//   the global->LDS latency hides under QK^T + softmax + PV. LDS 16->32 KB
//   (still 4 blocks/CU = 128 KB). Unlike R4's reg-staging attempt this costs
//   ZERO VGPRs (gl2lds is direct-to-LDS).
//   Mid barrier (P-alias WAR) is a RAW s_barrier + lgkmcnt(0): a __syncthreads
//   there would drain vmcnt(0) and kill the overlap. All QK^T ds_reads are
//   consumed by MFMAs before it, so lgkm-only is sufficient. End barrier stays
//   __syncthreads — its vmcnt(0) drain is exactly the "next tile ready"
//   guarantee, paid after a full compute phase of flight time.
// ---------------------------------------------------------------------------
__global__ __launch_bounds__(256, 4) void flash_attn_mfma(const unsigned short* __restrict__ Qh,
                                                          const unsigned short* __restrict__ Kh,
                                                          const unsigned short* __restrict__ Vtg,
                                                          unsigned short* __restrict__ Yh) {
    __shared__ __align__(16) unsigned short Ks[2][64 * 64]; // [buf][key][d]; P strips after QK^T
    __shared__ __align__(16) unsigned short Vt[2][64 * 64]; // [buf][d][key]

    const int pairi = blockIdx.x;          // 0 .. T/128-1
    const int h  = blockIdx.y;
    const int b  = blockIdx.z;
    const int hkv = h >> 2;
    const int tid = threadIdx.x;
    const int wave = tid >> 6;
    const int lane = tid & 63;
    const int m = lane & 15;
    const int quad = lane >> 4;

    // staging: thread t -> LDS slot t*16B (row r0=t>>3, chunk cs=t&7),
    // source chunk cg = cs ^ (r0&7)  (XOR applied on the global address)
    const int r0 = tid >> 3, cs = tid & 7, cg = cs ^ (r0 & 7);
    const int wbase = (tid & 192) * 16;
    char* KsB = (char*)Ks;                 // halves at +0 / +8192
    char* VtB = (char*)Vt;

    // P-strip addressing inside the current Ks half (wave-private 2KB quadrant):
    //   plain byte of key k, query m  =  m*128 + k*2 ; chunk-XOR swizzle ^ (m&7)
    const int m7 = m & 7;
    const int pwr = wave * 2048 + m * 128 + ((quad & 1) * 8);  // write base (+chunk sel per nt)
    const int qh2 = quad >> 1;
    const int prd = wave * 2048 + m * 128;                      // read base

    const unsigned short* gKbase = Kh + ((size_t)(b * T) * HKV + hkv) * D
                                      + (size_t)r0 * (HKV * D) + cg * 8;
    const unsigned short* gVbase = Vtg + ((size_t)(b * HKV + hkv) * D) * (size_t)T
                                       + (size_t)r0 * T + cg * 8;
    const size_t kStep = (size_t)64 * (HKV * D);
    const size_t kHalf = (size_t)32 * (HKV * D);

#pragma unroll 1
    for (int half = 0; half < 2; ++half) {
        const int qt = half ? pairi : (T / 64 - 1 - pairi);   // heavy tile, then light tile
        const int q0 = qt * 64;
        const int qmin = q0 + wave * 16;

        // Q B-frags: this wave's 16 queries q0 + wave*16 + m
        const unsigned short* qrow = Qh + ((size_t)((b * T + q0 + wave * 16 + m) * H) + h) * D;
        const bf16x8 qa0 = *(const bf16x8*)(qrow + quad * 8);
        const bf16x8 qa1 = *(const bf16x8*)(qrow + 32 + quad * 8);

        f32x4 o[4];
#pragma unroll
        for (int dt = 0; dt < 4; ++dt) o[dt] = (f32x4){0.f, 0.f, 0.f, 0.f};
        float ms = -1e30f, ls = 0.f;

        const unsigned short* gK = gKbase;
        const unsigned short* gV = gVbase;

        // prologue: stage tile 0 into half 0 (drained by the __syncthreads)
        gl2lds16(gK,         KsB + wbase);
        gl2lds16(gK + kHalf, KsB + 4096 + wbase);
        gl2lds16(gV,                  VtB + wbase);
        gl2lds16(gV + (size_t)32 * T, VtB + 4096 + wbase);
        gK += kStep;
        gV += 64;
        __syncthreads();

        for (int k0 = 0; k0 <= q0; k0 += 64) {
            const int cur = (k0 >> 6) & 1;
            char* KsC = KsB + cur * 8192;
            char* VtC = VtB + cur * 8192;

            // ---- issue tile t+1 staging into the OTHER half (flies all iter) ----
            if (k0 + 64 <= q0) {
                char* KsN = KsB + (cur ^ 1) * 8192;
                char* VtN = VtB + (cur ^ 1) * 8192;
                gl2lds16(gK,         KsN + wbase);
                gl2lds16(gK + kHalf, KsN + 4096 + wbase);
                gl2lds16(gV,                  VtN + wbase);
                gl2lds16(gV + (size_t)32 * T, VtN + 4096 + wbase);
                gK += kStep;
                gV += 64;
            }

            // ---- S^T = K · Q^T  (4 key-tiles of 16) ----
            f32x4 s[4];
            __builtin_amdgcn_s_setprio(1);
#pragma unroll
            for (int nt = 0; nt < 4; ++nt) {
                const int kmin = k0 + nt * 16;
                if (kmin > qmin + 15) {            // fully masked tile
                    s[nt] = (f32x4){-1e30f, -1e30f, -1e30f, -1e30f};
                    continue;
                }
                int row = nt * 16 + m;
                const bf16x8 ka0 = *(const bf16x8*)(KsC + row * 128 + ((quad ^ (m & 7)) * 16));
                const bf16x8 ka1 = *(const bf16x8*)(KsC + row * 128 + (((quad + 4) ^ (m & 7)) * 16));
                f32x4 acc = (f32x4){0.f, 0.f, 0.f, 0.f};
                acc = __builtin_amdgcn_mfma_f32_16x16x32_bf16(ka0, qa0, acc, 0, 0, 0);
                acc = __builtin_amdgcn_mfma_f32_16x16x32_bf16(ka1, qa1, acc, 0, 0, 0);
                if (kmin + 15 > qmin) {            // diagonal: elementwise mask
                    int c0 = qmin - kmin + m - 4 * quad;   // mask if r > c0
#pragma unroll
                    for (int r = 0; r < 4; ++r)
                        if (r > c0) acc[r] = -1e30f;
                }
                s[nt] = acc;
            }
            __builtin_amdgcn_s_setprio(0);

            // all waves done reading KsC -> it becomes the P strip buffer.
            // RAW barrier (lgkm-only): must NOT drain vmcnt (prefetch in flight).
            __builtin_amdgcn_sched_barrier(0);
            asm volatile("s_waitcnt lgkmcnt(0)" ::: "memory");
            __builtin_amdgcn_s_barrier();
            __builtin_amdgcn_sched_barrier(0);

            // ---- base-2 online softmax (lane owns query m; reduce across quads) ----
            float mx = s[0][0];
#pragma unroll
            for (int nt = 0; nt < 4; ++nt)
#pragma unroll
                for (int r = 0; r < 4; ++r) mx = fmaxf(mx, s[nt][r]);
            mx = fmaxf(mx, __shfl_xor(mx, 16));
            mx = fmaxf(mx, __shfl_xor(mx, 32));

            // defer-rescale: only pay alpha broadcast + O rescale when the running
            // max grew by more than THR (P values stay bounded by 2^THR = 256)
            float al = 1.0f;
            if (__any(mx > ms + 8.0f)) {
                float mnew = fmaxf(ms, mx);
                al = exp2f(ms - mnew);
                ms = mnew;
                float av[4];
#pragma unroll
                for (int r = 0; r < 4; ++r)
                    av[r] = __shfl(al, quad * 20 + r);   // lane with m' = quad*4+r
#pragma unroll
                for (int dt = 0; dt < 4; ++dt)
#pragma unroll
                    for (int r = 0; r < 4; ++r) o[dt][r] *= av[r];
            }

            float psum = 0.f;
#pragma unroll
            for (int nt = 0; nt < 4; ++nt) {
                float p0 = exp2f(s[nt][0] - ms);
                float p1 = exp2f(s[nt][1] - ms);
                float p2 = exp2f(s[nt][2] - ms);
                float p3 = exp2f(s[nt][3] - ms);
                psum += (p0 + p1) + (p2 + p3);
                uint2 w;
                w.x = cvt_pk_bf16(p0, p1);
                w.y = cvt_pk_bf16(p2, p3);
                // keys nt*16+quad*4..+3 of query m, chunk-XOR swizzled
                *(uint2*)(KsC + pwr + (((2 * nt + qh2) ^ m7) << 4)) = w;
            }
            psum += __shfl_xor(psum, 16);
            psum += __shfl_xor(psum, 32);
            ls = ls * al + psum;

            // ---- O += P · V ----
            const bf16x8 pa0 = *(const bf16x8*)(KsC + prd + ((quad ^ m7) << 4));
            const bf16x8 pa1 = *(const bf16x8*)(KsC + prd + (((quad + 4) ^ m7) << 4));
            __builtin_amdgcn_s_setprio(1);
#pragma unroll
            for (int dt = 0; dt < 4; ++dt) {
                int vrow = dt * 16 + m;
                const bf16x8 vb0 = *(const bf16x8*)(VtC + vrow * 128 + ((quad ^ (m & 7)) * 16));
                const bf16x8 vb1 = *(const bf16x8*)(VtC + vrow * 128 + (((quad + 4) ^ (m & 7)) * 16));
                o[dt] = __builtin_amdgcn_mfma_f32_16x16x32_bf16(pa0, vb0, o[dt], 0, 0, 0);
                o[dt] = __builtin_amdgcn_mfma_f32_16x16x32_bf16(pa1, vb1, o[dt], 0, 0, 0);
            }
            __builtin_amdgcn_s_setprio(0);
            // end barrier: drains vmcnt(0) (next tile landed) + lgkm, releases
            // this half's P strips / Vt for the following restage.
            __syncthreads();
        }

        // ---- epilogue: O / l -> bf16 y[b][t][h][d] ----
#pragma unroll
        for (int r = 0; r < 4; ++r) {
            float lv = __shfl(ls, quad * 20 + r);
            float inv = 1.0f / lv;
            int trow = q0 + wave * 16 + quad * 4 + r;
            unsigned short* yp = Yh + ((size_t)(b * T + trow) * H + h) * D;
#pragma unroll
            for (int dt = 0; dt < 4; ++dt)
                yp[dt * 16 + m] = f2bf(o[dt][r] * inv);
        }
    }
}

// ---------------------------------------------------------------------------
extern "C" void kernel_launch(void* const* d_in, const int* in_sizes, int n_in,
                              void* d_out, int out_size, void* d_ws, size_t ws_size,
                              hipStream_t stream) {
    const float* x  = (const float*)d_in[0];
    const float* Wq = (const float*)d_in[1];
    const float* Wk = (const float*)d_in[2];
    const float* Wv = (const float*)d_in[3];
    const float* Wc = (const float*)d_in[4];
    const int*  pos = (const int*)d_in[5];
    float* out = (float*)d_out;

    unsigned short* xh  = (unsigned short*)d_ws;           // contiguous with the 4 weight
    unsigned short* wqh = xh  + (size_t)B * T * C;         // buffers — fused cast relies on it
    unsigned short* wkh = wqh + (size_t)H * D * C;
    unsigned short* wvh = wkh + (size_t)HKV * D * C;
    unsigned short* wch = wvh + (size_t)HKV * D * C;
    unsigned short* qh  = wch + (size_t)C * C;
    unsigned short* kh  = qh  + (size_t)B * T * H * D;
    unsigned short* vh  = kh  + (size_t)B * T * HKV * D;
    unsigned short* vtg = vh  + (size_t)B * T * HKV * D;
    unsigned short* yh  = xh;                              // alias (xh dead after QKV)

    // 1) fused cast fp32 -> bf16 of x + Wq + Wk + Wv + Wc (one launch)
    const size_t cast_total = (size_t)B * T * C + (size_t)(H + 2 * HKV) * D * C + (size_t)C * C;
    cast_all_bf16<<<(unsigned)(cast_total / (256 * 8)), 256, 0, stream>>>(x, Wq, Wk, Wv, Wc, xh);

    // 2) fused QKV projection (bf16 MFMA, BK=64)
    dim3 g1((H * D + 2 * HKV * D) / 128, (B * T) / 128);
    qkv_gemm_bf16<<<g1, 256, 0, stream>>>(xh, wqh, wkh, wvh, qh, kh, vh);

    // 3) fused RoPE on q (scale folded) + k; V transpose
    const float QSCALE = SCALE * 1.4426950408889634f;  // SCALE * log2(e)
    rope_fused<<<(B * T * (H + HKV) * 32) / 256, 256, 0, stream>>>(qh, kh, pos, QSCALE);
    v_transpose<<<dim3(T / 64, HKV, B), 256, 0, stream>>>(vh, vtg);

    // 4) causal GQA flash attention (triangle-folded, K/V double-buffered)
    dim3 g2(T / 128, H, B);
    flash_attn_mfma<<<g2, 256, 0, stream>>>(qh, kh, vtg, yh);

    // 5) output projection (BK=64)
    dim3 g3(C / 128, (B * T) / 128);
    out_gemm_bf16<<<g3, 256, 0, stream>>>(yh, wch, out);
}